// Round 1
// baseline (907.875 us; speedup 1.0000x reference)
//
#include <hip/hip_runtime.h>
#include <stdint.h>

typedef unsigned short ushort_t;
typedef __attribute__((ext_vector_type(4))) float f32x4;
typedef __attribute__((ext_vector_type(8))) short s16x8;

#define DEVFN static __device__ __forceinline__

constexpr int B_   = 1024;
constexpr int P_   = 93528;   // upper-tri pairs of 432
constexpr int K1   = 93544;   // 16 + P_
constexpr int Kp   = 94208;   // padded K: 16 splits * 92 steps * 64
constexpr int SPLITS = 16;
constexpr int KCH  = Kp / SPLITS;  // 5888
constexpr int KSTEPS = KCH / 64;   // 92

DEVFN ushort_t f2bf(float f) {
  union { float f; unsigned int u; } x; x.f = f;
  unsigned int r = x.u + 0x7FFFu + ((x.u >> 16) & 1u);
  return (ushort_t)(r >> 16);
}

DEVFN void gload_lds16(const void* g, void* l) {
  __builtin_amdgcn_global_load_lds((const __attribute__((address_space(1))) unsigned int*)g,
                                   (__attribute__((address_space(3))) unsigned int*)l, 16, 0, 0);
}

// ---------- upper-triangle index table: iu[p] = i | (j<<16) ----------
__global__ __launch_bounds__(256) void k_iu(int* __restrict__ iu) {
  int p = blockIdx.x * 256 + threadIdx.x;
  if (p >= P_) return;
  float s = sqrtf((float)(748225 - 8 * p));      // 865^2 = 748225
  int i = (int)((865.0f - s) * 0.5f);
  if (i < 0) i = 0; if (i > 431) i = 431;
  while (i < 431 && (i + 1) * (865 - (i + 1)) / 2 <= p) ++i;
  while (i > 0 && i * (865 - i) / 2 > p) --i;
  int j = i + (p - i * (865 - i) / 2);
  iu[p] = i | (j << 16);
}

// ---------- generic MLP layer: 16 rows/block; col-split over blockIdx.y ----------
template<int K, int N, bool RELU, bool TROUT>
__global__ __launch_bounds__(256) void k_mlp(const float* __restrict__ in,
                                             const float* __restrict__ W,
                                             const float* __restrict__ bias,
                                             float* __restrict__ out) {
  __shared__ float xs[16 * K];
  int t = threadIdx.x, m0 = blockIdx.x * 16;
  const float4* src = (const float4*)(in + (size_t)m0 * K);
  for (int i = t; i < 16 * K / 4; i += 256) ((float4*)xs)[i] = src[i];
  __syncthreads();
  if (N >= 256) {
    int n = blockIdx.y * 256 + t;
    float acc[16];
    float bv = bias[n];
    #pragma unroll
    for (int r = 0; r < 16; ++r) acc[r] = bv;
    for (int k = 0; k < K; ++k) {
      float w = W[(size_t)k * N + n];
      #pragma unroll
      for (int r = 0; r < 16; ++r) acc[r] = fmaf(xs[r * K + k], w, acc[r]);
    }
    #pragma unroll
    for (int r = 0; r < 16; ++r) {
      float v = acc[r]; if (RELU) v = fmaxf(v, 0.f);
      if (TROUT) out[(size_t)n * B_ + m0 + r] = v;
      else       out[(size_t)(m0 + r) * N + n] = v;
    }
  } else {
    constexpr int RS = 256 / N;
    int n = t % N, r0 = t / N;
    float bv = bias[n];
    for (int r = r0; r < 16; r += RS) {
      float acc = bv;
      for (int k = 0; k < K; ++k) acc = fmaf(xs[r * K + k], W[k * N + n], acc);
      float v = RELU ? fmaxf(acc, 0.f) : acc;
      if (TROUT) out[(size_t)n * B_ + m0 + r] = v;
      else       out[(size_t)(m0 + r) * N + n] = v;
    }
  }
}

// ---------- embedding gather into xT rows 16..431 (xT is [432][1024] f32) ----------
__global__ __launch_bounds__(256) void k_emb(const int* __restrict__ sparse,
                                             const float* __restrict__ tbl,
                                             float* __restrict__ xT) {
  int f = blockIdx.x;
  int b = blockIdx.y * 256 + threadIdx.x;
  int idx = sparse[(size_t)b * 26 + f];
  const float4* src = (const float4*)(tbl + ((size_t)f * 100000 + idx) * 16);
  #pragma unroll
  for (int q = 0; q < 4; ++q) {
    float4 v = src[q];
    int r = 16 + f * 16 + q * 4;
    xT[(size_t)(r + 0) * B_ + b] = v.x;
    xT[(size_t)(r + 1) * B_ + b] = v.y;
    xT[(size_t)(r + 2) * B_ + b] = v.z;
    xT[(size_t)(r + 3) * B_ + b] = v.w;
  }
}

// ---------- Z generation: tile 64 m x 512 k, LDS transpose, bf16 out ----------
__global__ __launch_bounds__(256) void k_genz(const float* __restrict__ xT,
                                              const int* __restrict__ iu,
                                              ushort_t* __restrict__ Z) {
  __shared__ ushort_t zt[64 * 512];
  int t = threadIdx.x, l = t & 63, w = t >> 6;
  int mb = blockIdx.x * 64;
  int kt = blockIdx.y * 512;
  int kw = kt + w * 128;
  for (int g = 0; g < 16; ++g) {
    union { ushort_t u[8]; int4 v4; } r8;
    #pragma unroll
    for (int e = 0; e < 8; ++e) {
      int k = kw + g * 8 + e;
      float v;
      if (k < 16)       v = xT[(size_t)k * B_ + mb + l];
      else if (k < K1) {
        int ij = iu[k - 16];
        int i = ij & 0xFFFF, j = ij >> 16;
        v = xT[(size_t)i * B_ + mb + l] * xT[(size_t)j * B_ + mb + l];
      } else v = 0.f;
      r8.u[e] = f2bf(v);
    }
    int chunk = (w * 16 + g) ^ l;                 // swizzled chunk within row [0,64)
    *(int4*)&zt[l * 512 + chunk * 8] = r8.v4;
  }
  __syncthreads();
  int m = t >> 2, c0 = t & 3;
  ushort_t* dst = Z + (size_t)(mb + m) * Kp + kt;
  for (int q = 0; q < 16; ++q) {
    int c = c0 + q * 4;
    int chunk = c ^ m;
    *(int4*)(dst + c * 8) = *(const int4*)&zt[m * 512 + chunk * 8];
  }
}

// ---------- WT: transpose tw0 (K1 x 1024 f32) -> WT (1024 x Kp bf16) ----------
__global__ __launch_bounds__(256) void k_wt(const float* __restrict__ tw0,
                                            ushort_t* __restrict__ WT) {
  __shared__ float tile[64 * 65];
  int t = threadIdx.x;
  int k0 = blockIdx.x * 64, n0 = blockIdx.y * 64;
  int r = t >> 2, cq = t & 3;
  const float* src = tw0 + (size_t)(k0 + r) * 1024 + n0 + cq * 16;
  bool ok = (k0 + r) < K1;
  #pragma unroll
  for (int q = 0; q < 4; ++q) {
    float4 v = make_float4(0.f, 0.f, 0.f, 0.f);
    if (ok) v = *(const float4*)(src + q * 4);
    tile[r * 65 + cq * 16 + q * 4 + 0] = v.x;
    tile[r * 65 + cq * 16 + q * 4 + 1] = v.y;
    tile[r * 65 + cq * 16 + q * 4 + 2] = v.z;
    tile[r * 65 + cq * 16 + q * 4 + 3] = v.w;
  }
  __syncthreads();
  int nn = t >> 2, ch0 = (t & 3) * 2;
  ushort_t* dst = WT + (size_t)(n0 + nn) * Kp + k0;
  #pragma unroll
  for (int cc = 0; cc < 2; ++cc) {
    int ch = ch0 + cc;
    union { ushort_t u[8]; int4 v4; } o;
    #pragma unroll
    for (int e = 0; e < 8; ++e) o.u[e] = f2bf(tile[(ch * 8 + e) * 65 + nn]);
    *(int4*)(dst + ch * 8) = o.v4;
  }
}

// ---------- main bf16 GEMM: C(1024x1024) = Z @ WT^T, split-K into partials ----------
__global__ __launch_bounds__(512, 2) void k_gemm(const ushort_t* __restrict__ Z,
                                                 const ushort_t* __restrict__ WT,
                                                 float* __restrict__ part) {
  __shared__ ushort_t lA[256 * 64];
  __shared__ ushort_t lB[256 * 64];
  int t = threadIdx.x;
  int bid = blockIdx.x;
  int s = bid >> 4, tile = bid & 15;
  int m0 = (tile >> 2) * 256, n0 = (tile & 3) * 256;
  int kb = s * KCH;

  const ushort_t* pa[4]; const ushort_t* pb[4];
  ushort_t* la[4]; ushort_t* lb[4];
  #pragma unroll
  for (int i = 0; i < 4; ++i) {
    int slot = i * 512 + t;
    int r = slot >> 3, c = slot & 7;
    int cs = c ^ (r & 7);                         // inverse swizzle on global source
    pa[i] = Z  + (size_t)(m0 + r) * Kp + kb + cs * 8;
    pb[i] = WT + (size_t)(n0 + r) * Kp + kb + cs * 8;
    la[i] = &lA[slot * 8];
    lb[i] = &lB[slot * 8];
  }
  int w = t >> 6, l = t & 63;
  int wm = (w >> 2) * 128, wn = (w & 3) * 64;
  int lhi = l >> 4, llo = l & 15;

  f32x4 acc[8][4];
  #pragma unroll
  for (int a = 0; a < 8; ++a)
    #pragma unroll
    for (int b = 0; b < 4; ++b) acc[a][b] = f32x4{0.f, 0.f, 0.f, 0.f};

  for (int step = 0; step < KSTEPS; ++step) {
    int ko = step * 64;
    #pragma unroll
    for (int i = 0; i < 4; ++i) {
      gload_lds16(pa[i] + ko, la[i]);
      gload_lds16(pb[i] + ko, lb[i]);
    }
    asm volatile("s_waitcnt vmcnt(0)" ::: "memory");
    __syncthreads();
    #pragma unroll
    for (int ks = 0; ks < 2; ++ks) {
      s16x8 af[8], bfr[4];
      #pragma unroll
      for (int nf = 0; nf < 4; ++nf) {
        int row = wn + nf * 16 + llo;
        int ch = (ks * 4 + lhi) ^ (row & 7);      // swizzled frag read
        bfr[nf] = *(const s16x8*)&lB[row * 64 + ch * 8];
      }
      #pragma unroll
      for (int mf = 0; mf < 8; ++mf) {
        int row = wm + mf * 16 + llo;
        int ch = (ks * 4 + lhi) ^ (row & 7);
        af[mf] = *(const s16x8*)&lA[row * 64 + ch * 8];
      }
      #pragma unroll
      for (int mf = 0; mf < 8; ++mf)
        #pragma unroll
        for (int nf = 0; nf < 4; ++nf)
          acc[mf][nf] = __builtin_amdgcn_mfma_f32_16x16x32_bf16(af[mf], bfr[nf], acc[mf][nf], 0, 0, 0);
    }
    __syncthreads();
  }
  float* pbase = part + ((size_t)s << 20);
  #pragma unroll
  for (int mf = 0; mf < 8; ++mf)
    #pragma unroll
    for (int nf = 0; nf < 4; ++nf) {
      int n = n0 + wn + nf * 16 + llo;
      #pragma unroll
      for (int r = 0; r < 4; ++r) {
        int m = m0 + wm + mf * 16 + lhi * 4 + r;  // C layout: col=lane&15, row=(lane>>4)*4+reg
        pbase[(size_t)m * 1024 + n] = acc[mf][nf][r];
      }
    }
}

// ---------- reduce partials + bias + relu -> z1 ----------
__global__ __launch_bounds__(256) void k_red(const float* __restrict__ part,
                                             const float* __restrict__ bias,
                                             float* __restrict__ z1) {
  int idx = blockIdx.x * 256 + threadIdx.x;
  float a = bias[idx & 1023];
  #pragma unroll
  for (int s = 0; s < SPLITS; ++s) a += part[((size_t)s << 20) + idx];
  z1[idx] = fmaxf(a, 0.f);
}

// ---------- final layer: K=256 -> 1, wave reduction ----------
__global__ __launch_bounds__(256) void k_last(const float* __restrict__ z3,
                                              const float* __restrict__ w,
                                              const float* __restrict__ bias,
                                              float* __restrict__ out) {
  int t = threadIdx.x, l = t & 63, wv = t >> 6;
  int m = blockIdx.x * 4 + wv;
  float s = 0.f;
  #pragma unroll
  for (int c = 0; c < 4; ++c) s = fmaf(z3[(size_t)m * 256 + c * 64 + l], w[c * 64 + l], s);
  #pragma unroll
  for (int off = 32; off; off >>= 1) s += __shfl_down(s, off, 64);
  if (l == 0) out[m] = s + bias[0];
}

// ---------- fallback path (small workspace): fp32 fused-gen GEMM ----------
__global__ __launch_bounds__(256) void k_z1init(const float* __restrict__ bias, float* __restrict__ z1) {
  int idx = blockIdx.x * 256 + threadIdx.x;
  z1[idx] = bias[idx & 1023];
}
__global__ __launch_bounds__(256) void k_relu(float* __restrict__ z1) {
  int idx = blockIdx.x * 256 + threadIdx.x;
  z1[idx] = fmaxf(z1[idx], 0.f);
}
constexpr int FB_S = 8;
__global__ __launch_bounds__(256) void k_fbgemm(const float* __restrict__ xT,
                                                const int* __restrict__ iu,
                                                const float* __restrict__ tw0,
                                                float* __restrict__ z1) {
  __shared__ float zs[32 * 64];
  __shared__ float wsb[32 * 64];
  int t = threadIdx.x;
  int m0 = blockIdx.x * 64, n0 = blockIdx.y * 64, s = blockIdx.z;
  int kch = (K1 + FB_S - 1) / FB_S;
  int k0 = s * kch, kend = min(k0 + kch, K1);
  float acc[16];
  #pragma unroll
  for (int q = 0; q < 16; ++q) acc[q] = 0.f;
  int mm = t & 63, ng = t >> 6;
  for (int kk = k0; kk < kend; kk += 32) {
    __syncthreads();
    for (int sl = t; sl < 2048; sl += 256) {
      int kloc = sl >> 6, v6 = sl & 63;
      int k = kk + kloc;
      float zv = 0.f, wv = 0.f;
      if (k < kend) {
        if (k < 16) zv = xT[(size_t)k * B_ + m0 + v6];
        else {
          int ij = iu[k - 16];
          int i = ij & 0xFFFF, j = ij >> 16;
          zv = xT[(size_t)i * B_ + m0 + v6] * xT[(size_t)j * B_ + m0 + v6];
        }
        wv = tw0[(size_t)k * 1024 + n0 + v6];
      }
      zs[kloc * 64 + v6] = zv;
      wsb[kloc * 64 + v6] = wv;
    }
    __syncthreads();
    #pragma unroll 4
    for (int kloc = 0; kloc < 32; ++kloc) {
      float zv = zs[kloc * 64 + mm];
      #pragma unroll
      for (int q = 0; q < 16; ++q)
        acc[q] = fmaf(zv, wsb[kloc * 64 + ng * 16 + q], acc[q]);
    }
  }
  #pragma unroll
  for (int q = 0; q < 16; ++q)
    atomicAdd(&z1[(size_t)(m0 + mm) * 1024 + n0 + ng * 16 + q], acc[q]);
}

extern "C" void kernel_launch(void* const* d_in, const int* in_sizes, int n_in,
                              void* d_out, int out_size, void* d_ws, size_t ws_size,
                              hipStream_t stream) {
  const float* dense  = (const float*)d_in[0];
  const int*   sparse = (const int*)  d_in[1];
  const float* emb    = (const float*)d_in[2];
  const float* bw0 = (const float*)d_in[3];  const float* bb0 = (const float*)d_in[4];
  const float* bw1 = (const float*)d_in[5];  const float* bb1 = (const float*)d_in[6];
  const float* bw2 = (const float*)d_in[7];  const float* bb2 = (const float*)d_in[8];
  const float* bw3 = (const float*)d_in[9];  const float* bb3 = (const float*)d_in[10];
  const float* tw0 = (const float*)d_in[11]; const float* tb0 = (const float*)d_in[12];
  const float* tw1 = (const float*)d_in[13]; const float* tb1 = (const float*)d_in[14];
  const float* tw2 = (const float*)d_in[15]; const float* tb2 = (const float*)d_in[16];
  const float* tw3 = (const float*)d_in[17]; const float* tb3 = (const float*)d_in[18];
  float* out = (float*)d_out;

  char* ws = (char*)d_ws;
  size_t off = 0;
  auto alloc = [&](size_t bytes) -> char* {
    char* p = ws + off;
    off = (off + bytes + 255) & ~(size_t)255;
    return p;
  };
  float* h1 = (float*)alloc((size_t)1024 * 512 * 4);
  float* h2 = (float*)alloc((size_t)1024 * 256 * 4);
  float* h3 = (float*)alloc((size_t)1024 * 64 * 4);
  float* xT = (float*)alloc((size_t)432 * 1024 * 4);
  int*   iu = (int*)  alloc((size_t)P_ * 4);
  float* z1 = (float*)alloc((size_t)1024 * 1024 * 4);
  float* z2 = (float*)alloc((size_t)1024 * 512 * 4);
  float* z3 = (float*)alloc((size_t)1024 * 256 * 4);
  ushort_t* Z    = (ushort_t*)alloc((size_t)1024 * Kp * 2);
  ushort_t* WT   = (ushort_t*)alloc((size_t)1024 * Kp * 2);
  float*    part = (float*)   alloc((size_t)SPLITS * 1024 * 1024 * 4);
  bool big = (off <= ws_size);

  k_iu<<<366, 256, 0, stream>>>(iu);
  k_mlp<13, 512, true, false><<<dim3(64, 2), 256, 0, stream>>>(dense, bw0, bb0, h1);
  k_mlp<512, 256, true, false><<<dim3(64, 1), 256, 0, stream>>>(h1, bw1, bb1, h2);
  k_mlp<256, 64, true, false><<<dim3(64, 1), 256, 0, stream>>>(h2, bw2, bb2, h3);
  k_mlp<64, 16, true, true><<<dim3(64, 1), 256, 0, stream>>>(h3, bw3, bb3, xT);
  k_emb<<<dim3(26, 4), 256, 0, stream>>>(sparse, emb, xT);

  if (big) {
    k_genz<<<dim3(16, 184), 256, 0, stream>>>(xT, iu, Z);
    k_wt<<<dim3(1472, 16), 256, 0, stream>>>(tw0, WT);
    k_gemm<<<256, 512, 0, stream>>>(Z, WT, part);
    k_red<<<4096, 256, 0, stream>>>(part, tb0, z1);
  } else {
    k_z1init<<<4096, 256, 0, stream>>>(tb0, z1);
    k_fbgemm<<<dim3(16, 16, FB_S), 256, 0, stream>>>(xT, iu, tw0, z1);
    k_relu<<<4096, 256, 0, stream>>>(z1);
  }

  k_mlp<1024, 512, true, false><<<dim3(64, 2), 256, 0, stream>>>(z1, tw1, tb1, z2);
  k_mlp<512, 256, true, false><<<dim3(64, 1), 256, 0, stream>>>(z2, tw2, tb2, z3);
  k_last<<<256, 256, 0, stream>>>(z3, tw3, tb3, out);
}

// Round 2
// 741.075 us; speedup vs baseline: 1.2251x; 1.2251x over previous
//
#include <hip/hip_runtime.h>
#include <stdint.h>

typedef unsigned short ushort_t;
typedef __attribute__((ext_vector_type(4))) float f32x4;
typedef __attribute__((ext_vector_type(8))) short s16x8;

#define DEVFN static __device__ __forceinline__

constexpr int B_   = 1024;
constexpr int P_   = 93528;   // upper-tri pairs of 432
constexpr int K1   = 93544;   // 16 + P_
constexpr int Kp   = 94208;   // padded K: 16 splits * 92 steps * 64
constexpr int SPLITS = 16;
constexpr int KCH  = Kp / SPLITS;  // 5888
constexpr int KSTEPS = KCH / 64;   // 92

DEVFN ushort_t f2bf(float f) {
  union { float f; unsigned int u; } x; x.f = f;
  unsigned int r = x.u + 0x7FFFu + ((x.u >> 16) & 1u);
  return (ushort_t)(r >> 16);
}

DEVFN void gload_lds16(const void* g, void* l) {
  __builtin_amdgcn_global_load_lds((const __attribute__((address_space(1))) unsigned int*)g,
                                   (__attribute__((address_space(3))) unsigned int*)l, 16, 0, 0);
}

// ---------- upper-triangle index table: iu[p] = i | (j<<16) ----------
__global__ __launch_bounds__(256) void k_iu(int* __restrict__ iu) {
  int p = blockIdx.x * 256 + threadIdx.x;
  if (p >= P_) return;
  float s = sqrtf((float)(748225 - 8 * p));      // 865^2 = 748225
  int i = (int)((865.0f - s) * 0.5f);
  if (i < 0) i = 0; if (i > 431) i = 431;
  while (i < 431 && (i + 1) * (865 - (i + 1)) / 2 <= p) ++i;
  while (i > 0 && i * (865 - i) / 2 > p) --i;
  int j = i + (p - i * (865 - i) / 2);
  iu[p] = i | (j << 16);
}

// ---------- small MLP layer (bottom stack): 16 rows/block ----------
template<int K, int N, bool RELU, bool TROUT>
__global__ __launch_bounds__(256) void k_mlp(const float* __restrict__ in,
                                             const float* __restrict__ W,
                                             const float* __restrict__ bias,
                                             float* __restrict__ out) {
  __shared__ float xs[16 * K];
  int t = threadIdx.x, m0 = blockIdx.x * 16;
  const float4* src = (const float4*)(in + (size_t)m0 * K);
  for (int i = t; i < 16 * K / 4; i += 256) ((float4*)xs)[i] = src[i];
  __syncthreads();
  if (N >= 256) {
    int n = blockIdx.y * 256 + t;
    float acc[16];
    float bv = bias[n];
    #pragma unroll
    for (int r = 0; r < 16; ++r) acc[r] = bv;
    for (int k = 0; k < K; ++k) {
      float w = W[(size_t)k * N + n];
      #pragma unroll
      for (int r = 0; r < 16; ++r) acc[r] = fmaf(xs[r * K + k], w, acc[r]);
    }
    #pragma unroll
    for (int r = 0; r < 16; ++r) {
      float v = acc[r]; if (RELU) v = fmaxf(v, 0.f);
      if (TROUT) out[(size_t)n * B_ + m0 + r] = v;
      else       out[(size_t)(m0 + r) * N + n] = v;
    }
  } else {
    constexpr int RS = 256 / N;
    int n = t % N, r0 = t / N;
    float bv = bias[n];
    for (int r = r0; r < 16; r += RS) {
      float acc = bv;
      for (int k = 0; k < K; ++k) acc = fmaf(xs[r * K + k], W[k * N + n], acc);
      float v = RELU ? fmaxf(acc, 0.f) : acc;
      if (TROUT) out[(size_t)n * B_ + m0 + r] = v;
      else       out[(size_t)(m0 + r) * N + n] = v;
    }
  }
}

// ---------- tiled fp32 SGEMM for top MLP: C=relu(A@W+b), 32x64 tile ----------
template<int K, int N>
__global__ __launch_bounds__(256) void k_sgemm(const float* __restrict__ A,
                                               const float* __restrict__ W,
                                               const float* __restrict__ bias,
                                               float* __restrict__ C) {
  __shared__ float As[16][34];
  __shared__ float Bs[16][68];
  int t = threadIdx.x;
  int m0 = blockIdx.x * 32, n0 = blockIdx.y * 64;
  int tx = t & 15, ty = t >> 4;
  float acc[2][4];
  #pragma unroll
  for (int j = 0; j < 2; ++j)
    #pragma unroll
    for (int q = 0; q < 4; ++q) acc[j][q] = 0.f;
  int ar = t >> 3, ak = (t & 7) * 2;
  int bk = t >> 4, bn = (t & 15) * 4;
  for (int k0 = 0; k0 < K; k0 += 16) {
    float2 av = *(const float2*)&A[(size_t)(m0 + ar) * K + k0 + ak];
    float4 bv = *(const float4*)&W[(size_t)(k0 + bk) * N + n0 + bn];
    __syncthreads();
    As[ak][ar] = av.x; As[ak + 1][ar] = av.y;
    *(float4*)&Bs[bk][bn] = bv;
    __syncthreads();
    #pragma unroll
    for (int k = 0; k < 16; ++k) {
      float2 a = *(const float2*)&As[k][ty * 2];
      float4 b = *(const float4*)&Bs[k][tx * 4];
      acc[0][0] = fmaf(a.x, b.x, acc[0][0]); acc[0][1] = fmaf(a.x, b.y, acc[0][1]);
      acc[0][2] = fmaf(a.x, b.z, acc[0][2]); acc[0][3] = fmaf(a.x, b.w, acc[0][3]);
      acc[1][0] = fmaf(a.y, b.x, acc[1][0]); acc[1][1] = fmaf(a.y, b.y, acc[1][1]);
      acc[1][2] = fmaf(a.y, b.z, acc[1][2]); acc[1][3] = fmaf(a.y, b.w, acc[1][3]);
    }
  }
  #pragma unroll
  for (int j = 0; j < 2; ++j) {
    int m = m0 + ty * 2 + j;
    float4 o;
    o.x = fmaxf(acc[j][0] + bias[n0 + tx * 4 + 0], 0.f);
    o.y = fmaxf(acc[j][1] + bias[n0 + tx * 4 + 1], 0.f);
    o.z = fmaxf(acc[j][2] + bias[n0 + tx * 4 + 2], 0.f);
    o.w = fmaxf(acc[j][3] + bias[n0 + tx * 4 + 3], 0.f);
    *(float4*)&C[(size_t)m * N + n0 + tx * 4] = o;
  }
}

// ---------- embedding gather into xT rows 16..431 (xT is [432][1024] f32) ----------
__global__ __launch_bounds__(256) void k_emb(const int* __restrict__ sparse,
                                             const float* __restrict__ tbl,
                                             float* __restrict__ xT) {
  int f = blockIdx.x;
  int b = blockIdx.y * 256 + threadIdx.x;
  int idx = sparse[(size_t)b * 26 + f];
  const float4* src = (const float4*)(tbl + ((size_t)f * 100000 + idx) * 16);
  #pragma unroll
  for (int q = 0; q < 4; ++q) {
    float4 v = src[q];
    int r = 16 + f * 16 + q * 4;
    xT[(size_t)(r + 0) * B_ + b] = v.x;
    xT[(size_t)(r + 1) * B_ + b] = v.y;
    xT[(size_t)(r + 2) * B_ + b] = v.z;
    xT[(size_t)(r + 3) * B_ + b] = v.w;
  }
}

// ---------- Z generation: tile 64 m x 512 k, LDS transpose, bf16 out ----------
__global__ __launch_bounds__(256) void k_genz(const float* __restrict__ xT,
                                              const int* __restrict__ iu,
                                              ushort_t* __restrict__ Z) {
  __shared__ ushort_t zt[64 * 512];
  int t = threadIdx.x, l = t & 63, w = t >> 6;
  int mb = blockIdx.x * 64;
  int kt = blockIdx.y * 512;
  int kw = kt + w * 128;
  for (int g = 0; g < 16; ++g) {
    union { ushort_t u[8]; int4 v4; } r8;
    #pragma unroll
    for (int e = 0; e < 8; ++e) {
      int k = kw + g * 8 + e;
      float v;
      if (k < 16)       v = xT[(size_t)k * B_ + mb + l];
      else if (k < K1) {
        int ij = iu[k - 16];
        int i = ij & 0xFFFF, j = ij >> 16;
        v = xT[(size_t)i * B_ + mb + l] * xT[(size_t)j * B_ + mb + l];
      } else v = 0.f;
      r8.u[e] = f2bf(v);
    }
    int chunk = (w * 16 + g) ^ l;                 // swizzled chunk within row [0,64)
    *(int4*)&zt[l * 512 + chunk * 8] = r8.v4;
  }
  __syncthreads();
  int m = t >> 2, c0 = t & 3;
  ushort_t* dst = Z + (size_t)(mb + m) * Kp + kt;
  for (int q = 0; q < 16; ++q) {
    int c = c0 + q * 4;
    int chunk = c ^ m;
    *(int4*)(dst + c * 8) = *(const int4*)&zt[m * 512 + chunk * 8];
  }
}

// ---------- WT: transpose tw0 (K1 x 1024 f32) -> WT (1024 x Kp bf16) ----------
// tile: 256 k x 64 n per block
__global__ __launch_bounds__(256) void k_wt(const float* __restrict__ tw0,
                                            ushort_t* __restrict__ WT) {
  __shared__ ushort_t ls[256 * 68];
  int t = threadIdx.x;
  int k0 = blockIdx.x * 256, n0 = blockIdx.y * 64;
  int kr = t >> 2, c4 = t & 3;
  #pragma unroll
  for (int pass = 0; pass < 4; ++pass) {
    int kl = pass * 64 + kr;
    int k = k0 + kl;
    #pragma unroll
    for (int q = 0; q < 4; ++q) {
      float4 v = make_float4(0.f, 0.f, 0.f, 0.f);
      if (k < K1) v = *(const float4*)&tw0[(size_t)k * 1024 + n0 + q * 16 + c4 * 4];
      ushort_t* d = &ls[kl * 68 + q * 16 + c4 * 4];
      d[0] = f2bf(v.x); d[1] = f2bf(v.y); d[2] = f2bf(v.z); d[3] = f2bf(v.w);
    }
  }
  __syncthreads();
  int nl = t >> 2, kq = t & 3;
  ushort_t* dst = WT + (size_t)(n0 + nl) * Kp + k0 + kq * 64;
  #pragma unroll
  for (int j = 0; j < 8; ++j) {
    union { ushort_t u[8]; int4 v; } o;
    #pragma unroll
    for (int e = 0; e < 8; ++e) o.u[e] = ls[(kq * 64 + j * 8 + e) * 68 + nl];
    *(int4*)(dst + j * 8) = o.v;
  }
}

// ---------- main bf16 GEMM: 8-phase schedule, double-buffered LDS ----------
__global__ __launch_bounds__(512, 2) void k_gemm(const ushort_t* __restrict__ Z,
                                                 const ushort_t* __restrict__ WT,
                                                 float* __restrict__ part) {
  __shared__ ushort_t lds[65536];   // A: [2][16384] at 0; B: [2][16384] at 32768 (128 KB)
  int t = threadIdx.x;
  int bid = blockIdx.x;
  int s = bid >> 4, tile = bid & 15;
  int m0 = (tile >> 2) * 256, n0 = (tile & 3) * 256;
  int kb = s * KCH;

  int rr = t >> 3, cc = t & 7;
  int cs = cc ^ (rr & 7);                          // inverse swizzle on global source
  const ushort_t* pa0 = Z  + (size_t)(m0 + rr) * Kp + kb + cs * 8;
  const ushort_t* pb0 = WT + (size_t)(n0 + rr) * Kp + kb + cs * 8;
  const size_t rowStride = (size_t)64 * Kp;
  int l0 = t * 8;

  int w = t >> 6, l = t & 63;
  int wm = (w >> 2) * 128, wn = (w & 3) * 64;
  int lhi = l >> 4, llo = l & 15;

  f32x4 acc[8][4];
  #pragma unroll
  for (int a = 0; a < 8; ++a)
    #pragma unroll
    for (int b = 0; b < 4; ++b) acc[a][b] = f32x4{0.f, 0.f, 0.f, 0.f};

  // prologue: stage tile 0 into buffer 0
  #pragma unroll
  for (int i = 0; i < 4; ++i)
    gload_lds16(pa0 + i * rowStride, &lds[i * 4096 + l0]);
  #pragma unroll
  for (int i = 0; i < 4; ++i)
    gload_lds16(pb0 + i * rowStride, &lds[32768 + i * 4096 + l0]);
  asm volatile("s_waitcnt vmcnt(0)" ::: "memory");
  __builtin_amdgcn_s_barrier();

  for (int tt = 0; tt < KSTEPS; ++tt) {
    const ushort_t* Ab = &lds[(tt & 1) * 16384];
    const ushort_t* Bb = &lds[32768 + (tt & 1) * 16384];
    bool pf = (tt + 1 < KSTEPS);
    s16x8 bf[4][2];
    #pragma unroll
    for (int q = 0; q < 4; ++q) {
      if (q == 0) {
        #pragma unroll
        for (int nf = 0; nf < 4; ++nf)
          #pragma unroll
          for (int ks = 0; ks < 2; ++ks) {
            int row = wn + nf * 16 + llo;
            int ch = (ks * 4 + lhi) ^ (row & 7);
            bf[nf][ks] = *(const s16x8*)&Bb[row * 64 + ch * 8];
          }
      }
      s16x8 af[2][2];
      #pragma unroll
      for (int j = 0; j < 2; ++j)
        #pragma unroll
        for (int ks = 0; ks < 2; ++ks) {
          int row = wm + (q * 2 + j) * 16 + llo;
          int ch = (ks * 4 + lhi) ^ (row & 7);
          af[j][ks] = *(const s16x8*)&Ab[row * 64 + ch * 8];
        }
      if (q == 0 && pf) {
        ushort_t* d = &lds[((tt + 1) & 1) * 16384];
        const ushort_t* src = pa0 + (size_t)(tt + 1) * 64;
        #pragma unroll
        for (int i = 0; i < 4; ++i)
          gload_lds16(src + i * rowStride, d + i * 4096 + l0);
      }
      if (q == 1 && pf) {
        ushort_t* d = &lds[32768 + ((tt + 1) & 1) * 16384];
        const ushort_t* src = pb0 + (size_t)(tt + 1) * 64;
        #pragma unroll
        for (int i = 0; i < 4; ++i)
          gload_lds16(src + i * rowStride, d + i * 4096 + l0);
      }
      if (q == 3) asm volatile("s_waitcnt vmcnt(0)" ::: "memory");
      __builtin_amdgcn_s_barrier();
      asm volatile("s_waitcnt lgkmcnt(0)" ::: "memory");
      __builtin_amdgcn_s_setprio(1);
      #pragma unroll
      for (int j = 0; j < 2; ++j)
        #pragma unroll
        for (int nf = 0; nf < 4; ++nf)
          #pragma unroll
          for (int ks = 0; ks < 2; ++ks)
            acc[q * 2 + j][nf] = __builtin_amdgcn_mfma_f32_16x16x32_bf16(af[j][ks], bf[nf][ks], acc[q * 2 + j][nf], 0, 0, 0);
      __builtin_amdgcn_s_setprio(0);
      __builtin_amdgcn_s_barrier();
    }
  }

  float* pbase = part + ((size_t)s << 20);
  #pragma unroll
  for (int mf = 0; mf < 8; ++mf)
    #pragma unroll
    for (int nf = 0; nf < 4; ++nf) {
      int n = n0 + wn + nf * 16 + llo;
      #pragma unroll
      for (int r = 0; r < 4; ++r) {
        int m = m0 + wm + mf * 16 + lhi * 4 + r;  // C layout: col=lane&15, row=(lane>>4)*4+reg
        pbase[(size_t)m * 1024 + n] = acc[mf][nf][r];
      }
    }
}

// ---------- reduce partials + bias + relu -> z1 ----------
__global__ __launch_bounds__(256) void k_red(const float* __restrict__ part,
                                             const float* __restrict__ bias,
                                             float* __restrict__ z1) {
  int idx = blockIdx.x * 256 + threadIdx.x;
  float a = bias[idx & 1023];
  #pragma unroll
  for (int s = 0; s < SPLITS; ++s) a += part[((size_t)s << 20) + idx];
  z1[idx] = fmaxf(a, 0.f);
}

// ---------- final layer: K=256 -> 1, wave reduction ----------
__global__ __launch_bounds__(256) void k_last(const float* __restrict__ z3,
                                              const float* __restrict__ w,
                                              const float* __restrict__ bias,
                                              float* __restrict__ out) {
  int t = threadIdx.x, l = t & 63, wv = t >> 6;
  int m = blockIdx.x * 4 + wv;
  float s = 0.f;
  #pragma unroll
  for (int c = 0; c < 4; ++c) s = fmaf(z3[(size_t)m * 256 + c * 64 + l], w[c * 64 + l], s);
  #pragma unroll
  for (int off = 32; off; off >>= 1) s += __shfl_down(s, off, 64);
  if (l == 0) out[m] = s + bias[0];
}

// ---------- fallback path (small workspace): fp32 fused-gen GEMM ----------
__global__ __launch_bounds__(256) void k_z1init(const float* __restrict__ bias, float* __restrict__ z1) {
  int idx = blockIdx.x * 256 + threadIdx.x;
  z1[idx] = bias[idx & 1023];
}
__global__ __launch_bounds__(256) void k_relu(float* __restrict__ z1) {
  int idx = blockIdx.x * 256 + threadIdx.x;
  z1[idx] = fmaxf(z1[idx], 0.f);
}
constexpr int FB_S = 8;
__global__ __launch_bounds__(256) void k_fbgemm(const float* __restrict__ xT,
                                                const int* __restrict__ iu,
                                                const float* __restrict__ tw0,
                                                float* __restrict__ z1) {
  __shared__ float zs[32 * 64];
  __shared__ float wsb[32 * 64];
  int t = threadIdx.x;
  int m0 = blockIdx.x * 64, n0 = blockIdx.y * 64, s = blockIdx.z;
  int kch = (K1 + FB_S - 1) / FB_S;
  int k0 = s * kch, kend = min(k0 + kch, K1);
  float acc[16];
  #pragma unroll
  for (int q = 0; q < 16; ++q) acc[q] = 0.f;
  int mm = t & 63, ng = t >> 6;
  for (int kk = k0; kk < kend; kk += 32) {
    __syncthreads();
    for (int sl = t; sl < 2048; sl += 256) {
      int kloc = sl >> 6, v6 = sl & 63;
      int k = kk + kloc;
      float zv = 0.f, wv = 0.f;
      if (k < kend) {
        if (k < 16) zv = xT[(size_t)k * B_ + m0 + v6];
        else {
          int ij = iu[k - 16];
          int i = ij & 0xFFFF, j = ij >> 16;
          zv = xT[(size_t)i * B_ + m0 + v6] * xT[(size_t)j * B_ + m0 + v6];
        }
        wv = tw0[(size_t)k * 1024 + n0 + v6];
      }
      zs[kloc * 64 + v6] = zv;
      wsb[kloc * 64 + v6] = wv;
    }
    __syncthreads();
    #pragma unroll 4
    for (int kloc = 0; kloc < 32; ++kloc) {
      float zv = zs[kloc * 64 + mm];
      #pragma unroll
      for (int q = 0; q < 16; ++q)
        acc[q] = fmaf(zv, wsb[kloc * 64 + ng * 16 + q], acc[q]);
    }
  }
  #pragma unroll
  for (int q = 0; q < 16; ++q)
    atomicAdd(&z1[(size_t)(m0 + mm) * 1024 + n0 + ng * 16 + q], acc[q]);
}

extern "C" void kernel_launch(void* const* d_in, const int* in_sizes, int n_in,
                              void* d_out, int out_size, void* d_ws, size_t ws_size,
                              hipStream_t stream) {
  const float* dense  = (const float*)d_in[0];
  const int*   sparse = (const int*)  d_in[1];
  const float* emb    = (const float*)d_in[2];
  const float* bw0 = (const float*)d_in[3];  const float* bb0 = (const float*)d_in[4];
  const float* bw1 = (const float*)d_in[5];  const float* bb1 = (const float*)d_in[6];
  const float* bw2 = (const float*)d_in[7];  const float* bb2 = (const float*)d_in[8];
  const float* bw3 = (const float*)d_in[9];  const float* bb3 = (const float*)d_in[10];
  const float* tw0 = (const float*)d_in[11]; const float* tb0 = (const float*)d_in[12];
  const float* tw1 = (const float*)d_in[13]; const float* tb1 = (const float*)d_in[14];
  const float* tw2 = (const float*)d_in[15]; const float* tb2 = (const float*)d_in[16];
  const float* tw3 = (const float*)d_in[17]; const float* tb3 = (const float*)d_in[18];
  float* out = (float*)d_out;

  char* ws = (char*)d_ws;
  size_t off = 0;
  auto alloc = [&](size_t bytes) -> char* {
    char* p = ws + off;
    off = (off + bytes + 255) & ~(size_t)255;
    return p;
  };
  float* h1 = (float*)alloc((size_t)1024 * 512 * 4);
  float* h2 = (float*)alloc((size_t)1024 * 256 * 4);
  float* h3 = (float*)alloc((size_t)1024 * 64 * 4);
  float* xT = (float*)alloc((size_t)432 * 1024 * 4);
  int*   iu = (int*)  alloc((size_t)P_ * 4);
  float* z1 = (float*)alloc((size_t)1024 * 1024 * 4);
  float* z2 = (float*)alloc((size_t)1024 * 512 * 4);
  float* z3 = (float*)alloc((size_t)1024 * 256 * 4);
  ushort_t* Z    = (ushort_t*)alloc((size_t)1024 * Kp * 2);
  ushort_t* WT   = (ushort_t*)alloc((size_t)1024 * Kp * 2);
  float*    part = (float*)   alloc((size_t)SPLITS * 1024 * 1024 * 4);
  bool big = (off <= ws_size);

  k_iu<<<366, 256, 0, stream>>>(iu);
  k_mlp<13, 512, true, false><<<dim3(64, 2), 256, 0, stream>>>(dense, bw0, bb0, h1);
  k_mlp<512, 256, true, false><<<dim3(64, 1), 256, 0, stream>>>(h1, bw1, bb1, h2);
  k_mlp<256, 64, true, false><<<dim3(64, 1), 256, 0, stream>>>(h2, bw2, bb2, h3);
  k_mlp<64, 16, true, true><<<dim3(64, 1), 256, 0, stream>>>(h3, bw3, bb3, xT);
  k_emb<<<dim3(26, 4), 256, 0, stream>>>(sparse, emb, xT);

  if (big) {
    k_genz<<<dim3(16, 184), 256, 0, stream>>>(xT, iu, Z);
    k_wt<<<dim3(368, 16), 256, 0, stream>>>(tw0, WT);
    k_gemm<<<256, 512, 0, stream>>>(Z, WT, part);
    k_red<<<4096, 256, 0, stream>>>(part, tb0, z1);
  } else {
    k_z1init<<<4096, 256, 0, stream>>>(tb0, z1);
    k_fbgemm<<<dim3(16, 16, FB_S), 256, 0, stream>>>(xT, iu, tw0, z1);
    k_relu<<<4096, 256, 0, stream>>>(z1);
  }

  k_sgemm<1024, 512><<<dim3(32, 8), 256, 0, stream>>>(z1, tw1, tb1, z2);
  k_sgemm<512, 256><<<dim3(32, 4), 256, 0, stream>>>(z2, tw2, tb2, z3);
  k_last<<<256, 256, 0, stream>>>(z3, tw3, tb3, out);
}

// Round 3
// 632.439 us; speedup vs baseline: 1.4355x; 1.1718x over previous
//
#include <hip/hip_runtime.h>
#include <stdint.h>

typedef unsigned short ushort_t;
typedef __attribute__((ext_vector_type(4))) float f32x4;
typedef __attribute__((ext_vector_type(8))) short s16x8;

#define DEVFN static __device__ __forceinline__

constexpr int B_   = 1024;
constexpr int P_   = 93528;   // upper-tri pairs of 432
constexpr int K1   = 93544;   // 16 + P_
constexpr int Kp   = 94208;   // padded K: 16 splits * 92 steps * 64
constexpr int SPLITS = 16;
constexpr int KCH  = Kp / SPLITS;  // 5888
constexpr int KSTEPS = KCH / 64;   // 92
// xT layout: [434][1024]; row 432 = ones, row 433 = zeros (branch-free products)

DEVFN ushort_t f2bf(float f) {
  union { float f; unsigned int u; } x; x.f = f;
  unsigned int r = x.u + 0x7FFFu + ((x.u >> 16) & 1u);
  return (ushort_t)(r >> 16);
}

DEVFN void gload_lds16(const void* g, void* l) {
  __builtin_amdgcn_global_load_lds((const __attribute__((address_space(1))) unsigned int*)g,
                                   (__attribute__((address_space(3))) unsigned int*)l, 16, 0, 0);
}

// ---------- index table for ALL k: iu[k] = i | (j<<16) ----------
__global__ __launch_bounds__(256) void k_iu(int* __restrict__ iu) {
  int k = blockIdx.x * 256 + threadIdx.x;
  if (k >= Kp) return;
  int v;
  if (k < 16) v = k | (432 << 16);
  else if (k >= K1) v = 433 | (433 << 16);
  else {
    int p = k - 16;
    float s = sqrtf((float)(748225 - 8 * p));      // 865^2 = 748225
    int i = (int)((865.0f - s) * 0.5f);
    if (i < 0) i = 0; if (i > 431) i = 431;
    while (i < 431 && (i + 1) * (865 - (i + 1)) / 2 <= p) ++i;
    while (i > 0 && i * (865 - i) / 2 > p) --i;
    int j = i + (p - i * (865 - i) / 2);
    v = i | (j << 16);
  }
  iu[k] = v;
}

// ---------- fill xT rows 432 (ones) / 433 (zeros) ----------
__global__ __launch_bounds__(256) void k_pad(float* __restrict__ xT) {
  int t = blockIdx.x * 256 + threadIdx.x;
  xT[432 * 1024 + t] = (t < 1024) ? 1.f : 0.f;
}

// ---------- small MLP layer (bottom stack): 16 rows/block ----------
template<int K, int N, bool RELU, bool TROUT>
__global__ __launch_bounds__(256) void k_mlp(const float* __restrict__ in,
                                             const float* __restrict__ W,
                                             const float* __restrict__ bias,
                                             float* __restrict__ out) {
  __shared__ float xs[16 * K];
  int t = threadIdx.x, m0 = blockIdx.x * 16;
  const float4* src = (const float4*)(in + (size_t)m0 * K);
  for (int i = t; i < 16 * K / 4; i += 256) ((float4*)xs)[i] = src[i];
  __syncthreads();
  if (N >= 256) {
    int n = blockIdx.y * 256 + t;
    float acc[16];
    float bv = bias[n];
    #pragma unroll
    for (int r = 0; r < 16; ++r) acc[r] = bv;
    for (int k = 0; k < K; ++k) {
      float w = W[(size_t)k * N + n];
      #pragma unroll
      for (int r = 0; r < 16; ++r) acc[r] = fmaf(xs[r * K + k], w, acc[r]);
    }
    #pragma unroll
    for (int r = 0; r < 16; ++r) {
      float v = acc[r]; if (RELU) v = fmaxf(v, 0.f);
      if (TROUT) out[(size_t)n * B_ + m0 + r] = v;
      else       out[(size_t)(m0 + r) * N + n] = v;
    }
  } else {
    constexpr int RS = 256 / N;
    int n = t % N, r0 = t / N;
    float bv = bias[n];
    for (int r = r0; r < 16; r += RS) {
      float acc = bv;
      for (int k = 0; k < K; ++k) acc = fmaf(xs[r * K + k], W[k * N + n], acc);
      float v = RELU ? fmaxf(acc, 0.f) : acc;
      if (TROUT) out[(size_t)n * B_ + m0 + r] = v;
      else       out[(size_t)(m0 + r) * N + n] = v;
    }
  }
}

// ---------- tiled fp32 SGEMM for top MLP: C=relu(A@W+b), 32x64 tile ----------
template<int K, int N>
__global__ __launch_bounds__(256) void k_sgemm(const float* __restrict__ A,
                                               const float* __restrict__ W,
                                               const float* __restrict__ bias,
                                               float* __restrict__ C) {
  __shared__ float As[16][34];
  __shared__ float Bs[16][68];
  int t = threadIdx.x;
  int m0 = blockIdx.x * 32, n0 = blockIdx.y * 64;
  int tx = t & 15, ty = t >> 4;
  float acc[2][4];
  #pragma unroll
  for (int j = 0; j < 2; ++j)
    #pragma unroll
    for (int q = 0; q < 4; ++q) acc[j][q] = 0.f;
  int ar = t >> 3, ak = (t & 7) * 2;
  int bk = t >> 4, bn = (t & 15) * 4;
  for (int k0 = 0; k0 < K; k0 += 16) {
    float2 av = *(const float2*)&A[(size_t)(m0 + ar) * K + k0 + ak];
    float4 bv = *(const float4*)&W[(size_t)(k0 + bk) * N + n0 + bn];
    __syncthreads();
    As[ak][ar] = av.x; As[ak + 1][ar] = av.y;
    *(float4*)&Bs[bk][bn] = bv;
    __syncthreads();
    #pragma unroll
    for (int k = 0; k < 16; ++k) {
      float2 a = *(const float2*)&As[k][ty * 2];
      float4 b = *(const float4*)&Bs[k][tx * 4];
      acc[0][0] = fmaf(a.x, b.x, acc[0][0]); acc[0][1] = fmaf(a.x, b.y, acc[0][1]);
      acc[0][2] = fmaf(a.x, b.z, acc[0][2]); acc[0][3] = fmaf(a.x, b.w, acc[0][3]);
      acc[1][0] = fmaf(a.y, b.x, acc[1][0]); acc[1][1] = fmaf(a.y, b.y, acc[1][1]);
      acc[1][2] = fmaf(a.y, b.z, acc[1][2]); acc[1][3] = fmaf(a.y, b.w, acc[1][3]);
    }
  }
  #pragma unroll
  for (int j = 0; j < 2; ++j) {
    int m = m0 + ty * 2 + j;
    float4 o;
    o.x = fmaxf(acc[j][0] + bias[n0 + tx * 4 + 0], 0.f);
    o.y = fmaxf(acc[j][1] + bias[n0 + tx * 4 + 1], 0.f);
    o.z = fmaxf(acc[j][2] + bias[n0 + tx * 4 + 2], 0.f);
    o.w = fmaxf(acc[j][3] + bias[n0 + tx * 4 + 3], 0.f);
    *(float4*)&C[(size_t)m * N + n0 + tx * 4] = o;
  }
}

// ---------- embedding gather into xT rows 16..431 (xT is [434][1024] f32) ----------
__global__ __launch_bounds__(256) void k_emb(const int* __restrict__ sparse,
                                             const float* __restrict__ tbl,
                                             float* __restrict__ xT) {
  int f = blockIdx.x;
  int b = blockIdx.y * 256 + threadIdx.x;
  int idx = sparse[(size_t)b * 26 + f];
  const float4* src = (const float4*)(tbl + ((size_t)f * 100000 + idx) * 16);
  #pragma unroll
  for (int q = 0; q < 4; ++q) {
    float4 v = src[q];
    int r = 16 + f * 16 + q * 4;
    xT[(size_t)(r + 0) * B_ + b] = v.x;
    xT[(size_t)(r + 1) * B_ + b] = v.y;
    xT[(size_t)(r + 2) * B_ + b] = v.z;
    xT[(size_t)(r + 3) * B_ + b] = v.w;
  }
}

// ---------- Z generation v2: blocked layout Z[(k/8)][m][8], direct stores ----------
__global__ __launch_bounds__(256, 4) void k_genz(const float* __restrict__ xT,
                                                 const int* __restrict__ iu,
                                                 ushort_t* __restrict__ Z) {
  __shared__ int ls_iu[512];
  int t = threadIdx.x, l = t & 63, w = t >> 6;
  int mb = blockIdx.x * 64;
  int kt = blockIdx.y * 512;
  ls_iu[t] = iu[kt + t];
  ls_iu[256 + t] = iu[kt + 256 + t];
  __syncthreads();
  uint32_t moff = mb + l;
  int kw = w * 128;
  #pragma unroll 2
  for (int g = 0; g < 16; ++g) {
    int kloc = kw + g * 8;
    int4 ij0 = *(const int4*)&ls_iu[kloc];
    int4 ij1 = *(const int4*)&ls_iu[kloc + 4];
    float p[8];
    {
      int v0 = ij0.x, v1 = ij0.y, v2 = ij0.z, v3 = ij0.w;
      p[0] = xT[(uint32_t)((v0 & 0xFFFF) << 10) + moff] * xT[(uint32_t)((v0 >> 16) << 10) + moff];
      p[1] = xT[(uint32_t)((v1 & 0xFFFF) << 10) + moff] * xT[(uint32_t)((v1 >> 16) << 10) + moff];
      p[2] = xT[(uint32_t)((v2 & 0xFFFF) << 10) + moff] * xT[(uint32_t)((v2 >> 16) << 10) + moff];
      p[3] = xT[(uint32_t)((v3 & 0xFFFF) << 10) + moff] * xT[(uint32_t)((v3 >> 16) << 10) + moff];
      v0 = ij1.x; v1 = ij1.y; v2 = ij1.z; v3 = ij1.w;
      p[4] = xT[(uint32_t)((v0 & 0xFFFF) << 10) + moff] * xT[(uint32_t)((v0 >> 16) << 10) + moff];
      p[5] = xT[(uint32_t)((v1 & 0xFFFF) << 10) + moff] * xT[(uint32_t)((v1 >> 16) << 10) + moff];
      p[6] = xT[(uint32_t)((v2 & 0xFFFF) << 10) + moff] * xT[(uint32_t)((v2 >> 16) << 10) + moff];
      p[7] = xT[(uint32_t)((v3 & 0xFFFF) << 10) + moff] * xT[(uint32_t)((v3 >> 16) << 10) + moff];
    }
    union { uint32_t w[4]; int4 v4; } o;
    asm("v_cvt_pk_bf16_f32 %0, %1, %2" : "=v"(o.w[0]) : "v"(p[0]), "v"(p[1]));
    asm("v_cvt_pk_bf16_f32 %0, %1, %2" : "=v"(o.w[1]) : "v"(p[2]), "v"(p[3]));
    asm("v_cvt_pk_bf16_f32 %0, %1, %2" : "=v"(o.w[2]) : "v"(p[4]), "v"(p[5]));
    asm("v_cvt_pk_bf16_f32 %0, %1, %2" : "=v"(o.w[3]) : "v"(p[6]), "v"(p[7]));
    int kglob = kt + kloc;
    *(int4*)&Z[((size_t)(kglob >> 3) * 1024 + moff) * 8] = o.v4;
  }
}

// ---------- WT: transpose tw0 (K1 x 1024 f32) -> WT (1024 x Kp bf16) ----------
__global__ __launch_bounds__(256) void k_wt(const float* __restrict__ tw0,
                                            ushort_t* __restrict__ WT) {
  __shared__ ushort_t ls[256 * 68];
  int t = threadIdx.x;
  int k0 = blockIdx.x * 256, n0 = blockIdx.y * 64;
  int kr = t >> 2, c4 = t & 3;
  #pragma unroll
  for (int pass = 0; pass < 4; ++pass) {
    int kl = pass * 64 + kr;
    int k = k0 + kl;
    #pragma unroll
    for (int q = 0; q < 4; ++q) {
      float4 v = make_float4(0.f, 0.f, 0.f, 0.f);
      if (k < K1) v = *(const float4*)&tw0[(size_t)k * 1024 + n0 + q * 16 + c4 * 4];
      ushort_t* d = &ls[kl * 68 + q * 16 + c4 * 4];
      d[0] = f2bf(v.x); d[1] = f2bf(v.y); d[2] = f2bf(v.z); d[3] = f2bf(v.w);
    }
  }
  __syncthreads();
  int nl = t >> 2, kq = t & 3;
  ushort_t* dst = WT + (size_t)(n0 + nl) * Kp + k0 + kq * 64;
  #pragma unroll
  for (int j = 0; j < 8; ++j) {
    union { ushort_t u[8]; int4 v; } o;
    #pragma unroll
    for (int e = 0; e < 8; ++e) o.u[e] = ls[(kq * 64 + j * 8 + e) * 68 + nl];
    *(int4*)(dst + j * 8) = o.v;
  }
}

// ---------- main bf16 GEMM: 8-phase schedule, double-buffered LDS ----------
// A from blocked Z[(k/8)][m][8]; B from row-major WT[n][Kp]
__global__ __launch_bounds__(512, 2) void k_gemm(const ushort_t* __restrict__ Z,
                                                 const ushort_t* __restrict__ WT,
                                                 float* __restrict__ part) {
  __shared__ ushort_t lds[65536];   // A: [2][16384] at 0; B: [2][16384] at 32768 (128 KB)
  int t = threadIdx.x;
  int bid = blockIdx.x;
  int s = bid >> 4, tile = bid & 15;
  int m0 = (tile >> 2) * 256, n0 = (tile & 3) * 256;
  int kb = s * KCH;

  int rr = t >> 3, cc = t & 7;
  int cs = cc ^ (rr & 7);                          // inverse swizzle on global source
  const ushort_t* pa0 = Z + (((size_t)(kb >> 3) + cs) * 1024 + m0 + rr) * 8;
  const ushort_t* pb0 = WT + (size_t)(n0 + rr) * Kp + kb + cs * 8;
  const size_t rowStrideB = (size_t)64 * Kp;
  int l0 = t * 8;

  int w = t >> 6, l = t & 63;
  int wm = (w >> 2) * 128, wn = (w & 3) * 64;
  int lhi = l >> 4, llo = l & 15;

  f32x4 acc[8][4];
  #pragma unroll
  for (int a = 0; a < 8; ++a)
    #pragma unroll
    for (int b = 0; b < 4; ++b) acc[a][b] = f32x4{0.f, 0.f, 0.f, 0.f};

  // prologue: stage tile 0 into buffer 0
  #pragma unroll
  for (int i = 0; i < 4; ++i)
    gload_lds16(pa0 + i * 512, &lds[i * 4096 + l0]);          // +64 m rows = 512 ushorts
  #pragma unroll
  for (int i = 0; i < 4; ++i)
    gload_lds16(pb0 + i * rowStrideB, &lds[32768 + i * 4096 + l0]);
  asm volatile("s_waitcnt vmcnt(0)" ::: "memory");
  __builtin_amdgcn_s_barrier();

  for (int tt = 0; tt < KSTEPS; ++tt) {
    const ushort_t* Ab = &lds[(tt & 1) * 16384];
    const ushort_t* Bb = &lds[32768 + (tt & 1) * 16384];
    bool pf = (tt + 1 < KSTEPS);
    s16x8 bf[4][2];
    #pragma unroll
    for (int q = 0; q < 4; ++q) {
      if (q == 0) {
        #pragma unroll
        for (int nf = 0; nf < 4; ++nf)
          #pragma unroll
          for (int ks = 0; ks < 2; ++ks) {
            int row = wn + nf * 16 + llo;
            int ch = (ks * 4 + lhi) ^ (row & 7);
            bf[nf][ks] = *(const s16x8*)&Bb[row * 64 + ch * 8];
          }
      }
      s16x8 af[2][2];
      #pragma unroll
      for (int j = 0; j < 2; ++j)
        #pragma unroll
        for (int ks = 0; ks < 2; ++ks) {
          int row = wm + (q * 2 + j) * 16 + llo;
          int ch = (ks * 4 + lhi) ^ (row & 7);
          af[j][ks] = *(const s16x8*)&Ab[row * 64 + ch * 8];
        }
      if (q == 0 && pf) {
        ushort_t* d = &lds[((tt + 1) & 1) * 16384];
        const ushort_t* src = pa0 + (size_t)(tt + 1) * 65536;  // 8 chunks * 1024 m * 8
        #pragma unroll
        for (int i = 0; i < 4; ++i)
          gload_lds16(src + i * 512, d + i * 4096 + l0);
      }
      if (q == 1 && pf) {
        ushort_t* d = &lds[32768 + ((tt + 1) & 1) * 16384];
        const ushort_t* src = pb0 + (size_t)(tt + 1) * 64;
        #pragma unroll
        for (int i = 0; i < 4; ++i)
          gload_lds16(src + i * rowStrideB, d + i * 4096 + l0);
      }
      if (q == 3) asm volatile("s_waitcnt vmcnt(0)" ::: "memory");
      __builtin_amdgcn_s_barrier();
      asm volatile("s_waitcnt lgkmcnt(0)" ::: "memory");
      __builtin_amdgcn_s_setprio(1);
      #pragma unroll
      for (int j = 0; j < 2; ++j)
        #pragma unroll
        for (int nf = 0; nf < 4; ++nf)
          #pragma unroll
          for (int ks = 0; ks < 2; ++ks)
            acc[q * 2 + j][nf] = __builtin_amdgcn_mfma_f32_16x16x32_bf16(af[j][ks], bf[nf][ks], acc[q * 2 + j][nf], 0, 0, 0);
      __builtin_amdgcn_s_setprio(0);
      __builtin_amdgcn_s_barrier();
    }
  }

  float* pbase = part + ((size_t)s << 20);
  #pragma unroll
  for (int mf = 0; mf < 8; ++mf)
    #pragma unroll
    for (int nf = 0; nf < 4; ++nf) {
      int n = n0 + wn + nf * 16 + llo;
      #pragma unroll
      for (int r = 0; r < 4; ++r) {
        int m = m0 + wm + mf * 16 + lhi * 4 + r;  // C layout: col=lane&15, row=(lane>>4)*4+reg
        pbase[(size_t)m * 1024 + n] = acc[mf][nf][r];
      }
    }
}

// ---------- reduce partials + bias + relu -> z1 ----------
__global__ __launch_bounds__(256) void k_red(const float* __restrict__ part,
                                             const float* __restrict__ bias,
                                             float* __restrict__ z1) {
  int idx = blockIdx.x * 256 + threadIdx.x;
  float a = bias[idx & 1023];
  #pragma unroll
  for (int s = 0; s < SPLITS; ++s) a += part[((size_t)s << 20) + idx];
  z1[idx] = fmaxf(a, 0.f);
}

// ---------- final layer: K=256 -> 1, wave reduction ----------
__global__ __launch_bounds__(256) void k_last(const float* __restrict__ z3,
                                              const float* __restrict__ w,
                                              const float* __restrict__ bias,
                                              float* __restrict__ out) {
  int t = threadIdx.x, l = t & 63, wv = t >> 6;
  int m = blockIdx.x * 4 + wv;
  float s = 0.f;
  #pragma unroll
  for (int c = 0; c < 4; ++c) s = fmaf(z3[(size_t)m * 256 + c * 64 + l], w[c * 64 + l], s);
  #pragma unroll
  for (int off = 32; off; off >>= 1) s += __shfl_down(s, off, 64);
  if (l == 0) out[m] = s + bias[0];
}

// ---------- fallback path (small workspace): fp32 fused-gen GEMM ----------
__global__ __launch_bounds__(256) void k_z1init(const float* __restrict__ bias, float* __restrict__ z1) {
  int idx = blockIdx.x * 256 + threadIdx.x;
  z1[idx] = bias[idx & 1023];
}
__global__ __launch_bounds__(256) void k_relu(float* __restrict__ z1) {
  int idx = blockIdx.x * 256 + threadIdx.x;
  z1[idx] = fmaxf(z1[idx], 0.f);
}
constexpr int FB_S = 8;
__global__ __launch_bounds__(256) void k_fbgemm(const float* __restrict__ xT,
                                                const int* __restrict__ iu,
                                                const float* __restrict__ tw0,
                                                float* __restrict__ z1) {
  __shared__ float zs[32 * 64];
  __shared__ float wsb[32 * 64];
  int t = threadIdx.x;
  int m0 = blockIdx.x * 64, n0 = blockIdx.y * 64, s = blockIdx.z;
  int kch = (K1 + FB_S - 1) / FB_S;
  int k0 = s * kch, kend = min(k0 + kch, K1);
  float acc[16];
  #pragma unroll
  for (int q = 0; q < 16; ++q) acc[q] = 0.f;
  int mm = t & 63, ng = t >> 6;
  for (int kk = k0; kk < kend; kk += 32) {
    __syncthreads();
    for (int sl = t; sl < 2048; sl += 256) {
      int kloc = sl >> 6, v6 = sl & 63;
      int k = kk + kloc;
      float zv = 0.f, wv = 0.f;
      if (k < kend) {
        int ij = iu[k];
        int i = ij & 0xFFFF, j = ij >> 16;
        zv = xT[(size_t)i * B_ + m0 + v6] * xT[(size_t)j * B_ + m0 + v6];
        wv = tw0[(size_t)k * 1024 + n0 + v6];
      }
      zs[kloc * 64 + v6] = zv;
      wsb[kloc * 64 + v6] = wv;
    }
    __syncthreads();
    #pragma unroll 4
    for (int kloc = 0; kloc < 32; ++kloc) {
      float zv = zs[kloc * 64 + mm];
      #pragma unroll
      for (int q = 0; q < 16; ++q)
        acc[q] = fmaf(zv, wsb[kloc * 64 + ng * 16 + q], acc[q]);
    }
  }
  #pragma unroll
  for (int q = 0; q < 16; ++q)
    atomicAdd(&z1[(size_t)(m0 + mm) * 1024 + n0 + ng * 16 + q], acc[q]);
}

extern "C" void kernel_launch(void* const* d_in, const int* in_sizes, int n_in,
                              void* d_out, int out_size, void* d_ws, size_t ws_size,
                              hipStream_t stream) {
  const float* dense  = (const float*)d_in[0];
  const int*   sparse = (const int*)  d_in[1];
  const float* emb    = (const float*)d_in[2];
  const float* bw0 = (const float*)d_in[3];  const float* bb0 = (const float*)d_in[4];
  const float* bw1 = (const float*)d_in[5];  const float* bb1 = (const float*)d_in[6];
  const float* bw2 = (const float*)d_in[7];  const float* bb2 = (const float*)d_in[8];
  const float* bw3 = (const float*)d_in[9];  const float* bb3 = (const float*)d_in[10];
  const float* tw0 = (const float*)d_in[11]; const float* tb0 = (const float*)d_in[12];
  const float* tw1 = (const float*)d_in[13]; const float* tb1 = (const float*)d_in[14];
  const float* tw2 = (const float*)d_in[15]; const float* tb2 = (const float*)d_in[16];
  const float* tw3 = (const float*)d_in[17]; const float* tb3 = (const float*)d_in[18];
  float* out = (float*)d_out;

  char* ws = (char*)d_ws;
  size_t off = 0;
  auto alloc = [&](size_t bytes) -> char* {
    char* p = ws + off;
    off = (off + bytes + 255) & ~(size_t)255;
    return p;
  };
  float* h1 = (float*)alloc((size_t)1024 * 512 * 4);
  float* h2 = (float*)alloc((size_t)1024 * 256 * 4);
  float* h3 = (float*)alloc((size_t)1024 * 64 * 4);
  float* xT = (float*)alloc((size_t)434 * 1024 * 4);
  int*   iu = (int*)  alloc((size_t)Kp * 4);
  float* z1 = (float*)alloc((size_t)1024 * 1024 * 4);
  float* z2 = (float*)alloc((size_t)1024 * 512 * 4);
  float* z3 = (float*)alloc((size_t)1024 * 256 * 4);
  ushort_t* Z    = (ushort_t*)alloc((size_t)1024 * Kp * 2);
  ushort_t* WT   = (ushort_t*)alloc((size_t)1024 * Kp * 2);
  float*    part = (float*)   alloc((size_t)SPLITS * 1024 * 1024 * 4);
  bool big = (off <= ws_size);

  k_iu<<<368, 256, 0, stream>>>(iu);
  k_pad<<<8, 256, 0, stream>>>(xT);
  k_mlp<13, 512, true, false><<<dim3(64, 2), 256, 0, stream>>>(dense, bw0, bb0, h1);
  k_mlp<512, 256, true, false><<<dim3(64, 1), 256, 0, stream>>>(h1, bw1, bb1, h2);
  k_mlp<256, 64, true, false><<<dim3(64, 1), 256, 0, stream>>>(h2, bw2, bb2, h3);
  k_mlp<64, 16, true, true><<<dim3(64, 1), 256, 0, stream>>>(h3, bw3, bb3, xT);
  k_emb<<<dim3(26, 4), 256, 0, stream>>>(sparse, emb, xT);

  if (big) {
    k_genz<<<dim3(16, 184), 256, 0, stream>>>(xT, iu, Z);
    k_wt<<<dim3(368, 16), 256, 0, stream>>>(tw0, WT);
    k_gemm<<<256, 512, 0, stream>>>(Z, WT, part);
    k_red<<<4096, 256, 0, stream>>>(part, tb0, z1);
  } else {
    k_z1init<<<4096, 256, 0, stream>>>(tb0, z1);
    k_fbgemm<<<dim3(16, 16, FB_S), 256, 0, stream>>>(xT, iu, tw0, z1);
    k_relu<<<4096, 256, 0, stream>>>(z1);
  }

  k_sgemm<1024, 512><<<dim3(32, 8), 256, 0, stream>>>(z1, tw1, tb1, z2);
  k_sgemm<512, 256><<<dim3(32, 4), 256, 0, stream>>>(z2, tw2, tb2, z3);
  k_last<<<256, 256, 0, stream>>>(z3, tw3, tb3, out);
}

// Round 4
// 581.773 us; speedup vs baseline: 1.5605x; 1.0871x over previous
//
#include <hip/hip_runtime.h>
#include <stdint.h>

typedef unsigned short ushort_t;
typedef __attribute__((ext_vector_type(4))) float f32x4;
typedef __attribute__((ext_vector_type(8))) short s16x8;

#define DEVFN static __device__ __forceinline__

constexpr int B_   = 1024;
constexpr int P_   = 93528;   // upper-tri pairs of 432
constexpr int K1   = 93544;   // 16 + P_
constexpr int Kp   = 94208;   // padded K: 16 splits * 92 steps * 64
constexpr int SPLITS = 16;
constexpr int KCH  = Kp / SPLITS;  // 5888
constexpr int KSTEPS = KCH / 64;   // 92
// xT layout: [434][1024]; row 432 = ones, row 433 = zeros (branch-free products)

DEVFN ushort_t f2bf(float f) {
  union { float f; unsigned int u; } x; x.f = f;
  unsigned int r = x.u + 0x7FFFu + ((x.u >> 16) & 1u);
  return (ushort_t)(r >> 16);
}

DEVFN void gload_lds16(const void* g, void* l) {
  __builtin_amdgcn_global_load_lds((const __attribute__((address_space(1))) unsigned int*)g,
                                   (__attribute__((address_space(3))) unsigned int*)l, 16, 0, 0);
}

// ---------- index table for ALL k: iu[k] = i | (j<<16); also init xT pad rows ----------
__global__ __launch_bounds__(256) void k_iu(int* __restrict__ iu, float* __restrict__ xT) {
  int k = blockIdx.x * 256 + threadIdx.x;
  if (blockIdx.x < 8) {
    int idx = blockIdx.x * 256 + threadIdx.x;   // 0..2047
    xT[432 * 1024 + idx] = (idx < 1024) ? 1.f : 0.f;
  }
  if (k >= Kp) return;
  int v;
  if (k < 16) v = k | (432 << 16);
  else if (k >= K1) v = 433 | (433 << 16);
  else {
    int p = k - 16;
    float s = sqrtf((float)(748225 - 8 * p));      // 865^2 = 748225
    int i = (int)((865.0f - s) * 0.5f);
    if (i < 0) i = 0; if (i > 431) i = 431;
    while (i < 431 && (i + 1) * (865 - (i + 1)) / 2 <= p) ++i;
    while (i > 0 && i * (865 - i) / 2 > p) --i;
    int j = i + (p - i * (865 - i) / 2);
    v = i | (j << 16);
  }
  iu[k] = v;
}

// ---------- fused bottom MLP: 13->512->256->64->16, 16 rows/block, xT^T out ----------
__global__ __launch_bounds__(256) void k_bot(const float* __restrict__ dense,
    const float* __restrict__ bw0, const float* __restrict__ bb0,
    const float* __restrict__ bw1, const float* __restrict__ bb1,
    const float* __restrict__ bw2, const float* __restrict__ bb2,
    const float* __restrict__ bw3, const float* __restrict__ bb3,
    float* __restrict__ xT) {
  __shared__ float xs[16 * 13];
  __shared__ float h1[16 * 512];
  __shared__ float h2[16 * 256];
  __shared__ float h3[16 * 64];
  int t = threadIdx.x, m0 = blockIdx.x * 16;
  if (t < 208) xs[t] = dense[m0 * 13 + t];
  __syncthreads();
  // L1: 13 -> 512 (two n-halves per thread)
  #pragma unroll
  for (int h = 0; h < 2; ++h) {
    int n = h * 256 + t;
    float a[16];
    float bv = bb0[n];
    #pragma unroll
    for (int r = 0; r < 16; ++r) a[r] = bv;
    for (int k = 0; k < 13; ++k) {
      float w = bw0[k * 512 + n];
      #pragma unroll
      for (int r = 0; r < 16; ++r) a[r] = fmaf(xs[r * 13 + k], w, a[r]);
    }
    #pragma unroll
    for (int r = 0; r < 16; ++r) h1[r * 512 + n] = fmaxf(a[r], 0.f);
  }
  __syncthreads();
  // L2: 512 -> 256 (n = t)
  {
    int n = t;
    float a[16];
    float bv = bb1[n];
    #pragma unroll
    for (int r = 0; r < 16; ++r) a[r] = bv;
    for (int k = 0; k < 512; ++k) {
      float w = bw1[k * 256 + n];
      #pragma unroll
      for (int r = 0; r < 16; ++r) a[r] = fmaf(h1[r * 512 + k], w, a[r]);
    }
    #pragma unroll
    for (int r = 0; r < 16; ++r) h2[r * 256 + n] = fmaxf(a[r], 0.f);
  }
  __syncthreads();
  // L3: 256 -> 64 (n = t&63, rows t>>6 + 4i)
  {
    int n = t & 63, r0 = t >> 6;
    float a[4];
    float bv = bb2[n];
    #pragma unroll
    for (int i = 0; i < 4; ++i) a[i] = bv;
    for (int k = 0; k < 256; ++k) {
      float w = bw2[k * 64 + n];
      #pragma unroll
      for (int i = 0; i < 4; ++i) a[i] = fmaf(h2[(r0 + 4 * i) * 256 + k], w, a[i]);
    }
    #pragma unroll
    for (int i = 0; i < 4; ++i) h3[(r0 + 4 * i) * 64 + n] = fmaxf(a[i], 0.f);
  }
  __syncthreads();
  // L4: 64 -> 16 (n = t&15, row = t>>4), transposed store to xT
  {
    int n = t & 15, r = t >> 4;
    float a = bb3[n];
    for (int k = 0; k < 64; ++k) a = fmaf(h3[r * 64 + k], bw3[k * 16 + n], a);
    xT[(size_t)n * B_ + m0 + r] = fmaxf(a, 0.f);
  }
}

// ---------- tiled fp32 SGEMM for top MLP: C=relu(A@W+b), 32x64 tile ----------
template<int K, int N>
__global__ __launch_bounds__(256) void k_sgemm(const float* __restrict__ A,
                                               const float* __restrict__ W,
                                               const float* __restrict__ bias,
                                               float* __restrict__ C) {
  __shared__ float As[16][34];
  __shared__ float Bs[16][68];
  int t = threadIdx.x;
  int m0 = blockIdx.x * 32, n0 = blockIdx.y * 64;
  int tx = t & 15, ty = t >> 4;
  float acc[2][4];
  #pragma unroll
  for (int j = 0; j < 2; ++j)
    #pragma unroll
    for (int q = 0; q < 4; ++q) acc[j][q] = 0.f;
  int ar = t >> 3, ak = (t & 7) * 2;
  int bk = t >> 4, bn = (t & 15) * 4;
  for (int k0 = 0; k0 < K; k0 += 16) {
    float2 av = *(const float2*)&A[(size_t)(m0 + ar) * K + k0 + ak];
    float4 bv = *(const float4*)&W[(size_t)(k0 + bk) * N + n0 + bn];
    __syncthreads();
    As[ak][ar] = av.x; As[ak + 1][ar] = av.y;
    *(float4*)&Bs[bk][bn] = bv;
    __syncthreads();
    #pragma unroll
    for (int k = 0; k < 16; ++k) {
      float2 a = *(const float2*)&As[k][ty * 2];
      float4 b = *(const float4*)&Bs[k][tx * 4];
      acc[0][0] = fmaf(a.x, b.x, acc[0][0]); acc[0][1] = fmaf(a.x, b.y, acc[0][1]);
      acc[0][2] = fmaf(a.x, b.z, acc[0][2]); acc[0][3] = fmaf(a.x, b.w, acc[0][3]);
      acc[1][0] = fmaf(a.y, b.x, acc[1][0]); acc[1][1] = fmaf(a.y, b.y, acc[1][1]);
      acc[1][2] = fmaf(a.y, b.z, acc[1][2]); acc[1][3] = fmaf(a.y, b.w, acc[1][3]);
    }
  }
  #pragma unroll
  for (int j = 0; j < 2; ++j) {
    int m = m0 + ty * 2 + j;
    float4 o;
    o.x = fmaxf(acc[j][0] + bias[n0 + tx * 4 + 0], 0.f);
    o.y = fmaxf(acc[j][1] + bias[n0 + tx * 4 + 1], 0.f);
    o.z = fmaxf(acc[j][2] + bias[n0 + tx * 4 + 2], 0.f);
    o.w = fmaxf(acc[j][3] + bias[n0 + tx * 4 + 3], 0.f);
    *(float4*)&C[(size_t)m * N + n0 + tx * 4] = o;
  }
}

// ---------- embedding gather into xT rows 16..431 (xT is [434][1024] f32) ----------
__global__ __launch_bounds__(256) void k_emb(const int* __restrict__ sparse,
                                             const float* __restrict__ tbl,
                                             float* __restrict__ xT) {
  int f = blockIdx.x;
  int b = blockIdx.y * 256 + threadIdx.x;
  int idx = sparse[(size_t)b * 26 + f];
  const float4* src = (const float4*)(tbl + ((size_t)f * 100000 + idx) * 16);
  #pragma unroll
  for (int q = 0; q < 4; ++q) {
    float4 v = src[q];
    int r = 16 + f * 16 + q * 4;
    xT[(size_t)(r + 0) * B_ + b] = v.x;
    xT[(size_t)(r + 1) * B_ + b] = v.y;
    xT[(size_t)(r + 2) * B_ + b] = v.z;
    xT[(size_t)(r + 3) * B_ + b] = v.w;
  }
}

// ---------- Z generation: blocked layout Z[(k/8)][m][8], direct stores ----------
__global__ __launch_bounds__(256, 4) void k_genz(const float* __restrict__ xT,
                                                 const int* __restrict__ iu,
                                                 ushort_t* __restrict__ Z) {
  __shared__ int ls_iu[512];
  int t = threadIdx.x, l = t & 63, w = t >> 6;
  int mb = blockIdx.x * 64;
  int kt = blockIdx.y * 512;
  ls_iu[t] = iu[kt + t];
  ls_iu[256 + t] = iu[kt + 256 + t];
  __syncthreads();
  uint32_t moff = mb + l;
  int kw = w * 128;
  #pragma unroll 2
  for (int g = 0; g < 16; ++g) {
    int kloc = kw + g * 8;
    int4 ij0 = *(const int4*)&ls_iu[kloc];
    int4 ij1 = *(const int4*)&ls_iu[kloc + 4];
    float p[8];
    {
      int v0 = ij0.x, v1 = ij0.y, v2 = ij0.z, v3 = ij0.w;
      p[0] = xT[(uint32_t)((v0 & 0xFFFF) << 10) + moff] * xT[(uint32_t)((v0 >> 16) << 10) + moff];
      p[1] = xT[(uint32_t)((v1 & 0xFFFF) << 10) + moff] * xT[(uint32_t)((v1 >> 16) << 10) + moff];
      p[2] = xT[(uint32_t)((v2 & 0xFFFF) << 10) + moff] * xT[(uint32_t)((v2 >> 16) << 10) + moff];
      p[3] = xT[(uint32_t)((v3 & 0xFFFF) << 10) + moff] * xT[(uint32_t)((v3 >> 16) << 10) + moff];
      v0 = ij1.x; v1 = ij1.y; v2 = ij1.z; v3 = ij1.w;
      p[4] = xT[(uint32_t)((v0 & 0xFFFF) << 10) + moff] * xT[(uint32_t)((v0 >> 16) << 10) + moff];
      p[5] = xT[(uint32_t)((v1 & 0xFFFF) << 10) + moff] * xT[(uint32_t)((v1 >> 16) << 10) + moff];
      p[6] = xT[(uint32_t)((v2 & 0xFFFF) << 10) + moff] * xT[(uint32_t)((v2 >> 16) << 10) + moff];
      p[7] = xT[(uint32_t)((v3 & 0xFFFF) << 10) + moff] * xT[(uint32_t)((v3 >> 16) << 10) + moff];
    }
    union { uint32_t w[4]; int4 v4; } o;
    asm("v_cvt_pk_bf16_f32 %0, %1, %2" : "=v"(o.w[0]) : "v"(p[0]), "v"(p[1]));
    asm("v_cvt_pk_bf16_f32 %0, %1, %2" : "=v"(o.w[1]) : "v"(p[2]), "v"(p[3]));
    asm("v_cvt_pk_bf16_f32 %0, %1, %2" : "=v"(o.w[2]) : "v"(p[4]), "v"(p[5]));
    asm("v_cvt_pk_bf16_f32 %0, %1, %2" : "=v"(o.w[3]) : "v"(p[6]), "v"(p[7]));
    int kglob = kt + kloc;
    *(int4*)&Z[((size_t)(kglob >> 3) * 1024 + moff) * 8] = o.v4;
  }
}

// ---------- WT: transpose tw0 (K1 x 1024 f32) -> WT (1024 x Kp bf16) ----------
__global__ __launch_bounds__(256) void k_wt(const float* __restrict__ tw0,
                                            ushort_t* __restrict__ WT) {
  __shared__ ushort_t ls[256 * 68];
  int t = threadIdx.x;
  int k0 = blockIdx.x * 256, n0 = blockIdx.y * 64;
  int kr = t >> 2, c4 = t & 3;
  #pragma unroll
  for (int pass = 0; pass < 4; ++pass) {
    int kl = pass * 64 + kr;
    int k = k0 + kl;
    #pragma unroll
    for (int q = 0; q < 4; ++q) {
      float4 v = make_float4(0.f, 0.f, 0.f, 0.f);
      if (k < K1) v = *(const float4*)&tw0[(size_t)k * 1024 + n0 + q * 16 + c4 * 4];
      ushort_t* d = &ls[kl * 68 + q * 16 + c4 * 4];
      d[0] = f2bf(v.x); d[1] = f2bf(v.y); d[2] = f2bf(v.z); d[3] = f2bf(v.w);
    }
  }
  __syncthreads();
  int nl = t >> 2, kq = t & 3;
  ushort_t* dst = WT + (size_t)(n0 + nl) * Kp + k0 + kq * 64;
  #pragma unroll
  for (int j = 0; j < 8; ++j) {
    union { ushort_t u[8]; int4 v; } o;
    #pragma unroll
    for (int e = 0; e < 8; ++e) o.u[e] = ls[(kq * 64 + j * 8 + e) * 68 + nl];
    *(int4*)(dst + j * 8) = o.v;
  }
}

// ---------- main bf16 GEMM: counted-vmcnt pipeline, double-buffered LDS ----------
// A from blocked Z[(k/8)][m][8]; B from row-major WT[n][Kp]
// Chunk dependency: phase q reads A chunks {0,2} (q<2) / {1,3} (q>=2); B all at q0.
// Issue order per tile (canonical): B0,B1,B2,B3,A0,A2,A1,A3 spread over prev tile's phases.
// Waits: vmcnt(2)@q0 (allow A1,A3 of current), vmcnt(4)@q2 (allow B0-3 of next).
__global__ __launch_bounds__(512, 2) void k_gemm(const ushort_t* __restrict__ Z,
                                                 const ushort_t* __restrict__ WT,
                                                 float* __restrict__ part) {
  __shared__ ushort_t lds[65536];   // A: [2][16384] at 0; B: [2][16384] at 32768 (128 KB)
  int t = threadIdx.x;
  int bid = blockIdx.x;
  int s = bid >> 4, tile = bid & 15;
  int m0 = (tile >> 2) * 256, n0 = (tile & 3) * 256;
  int kb = s * KCH;

  int rr = t >> 3, cc = t & 7;
  int cs = cc ^ (rr & 7);                          // inverse swizzle on global source
  const ushort_t* pa0 = Z + (((size_t)(kb >> 3) + cs) * 1024 + m0 + rr) * 8;
  const ushort_t* pb0 = WT + (size_t)(n0 + rr) * Kp + kb + cs * 8;
  const size_t rowStrideB = (size_t)64 * Kp;
  int l0 = t * 8;

  int w = t >> 6, l = t & 63;
  int wm = (w >> 2) * 128, wn = (w & 3) * 64;
  int lhi = l >> 4, llo = l & 15;

  f32x4 acc[8][4];
  #pragma unroll
  for (int a = 0; a < 8; ++a)
    #pragma unroll
    for (int b = 0; b < 4; ++b) acc[a][b] = f32x4{0.f, 0.f, 0.f, 0.f};

  // prologue: stage tile 0 into buffer 0, canonical order, NO drain
  #pragma unroll
  for (int i = 0; i < 4; ++i)
    gload_lds16(pb0 + i * rowStrideB, &lds[32768 + i * 4096 + l0]);
  gload_lds16(pa0,            &lds[0 * 4096 + l0]);
  gload_lds16(pa0 + 2 * 512,  &lds[2 * 4096 + l0]);
  gload_lds16(pa0 + 1 * 512,  &lds[1 * 4096 + l0]);
  gload_lds16(pa0 + 3 * 512,  &lds[3 * 4096 + l0]);

  for (int tt = 0; tt < KSTEPS; ++tt) {
    const ushort_t* Ab = &lds[(tt & 1) * 16384];
    const ushort_t* Bb = &lds[32768 + (tt & 1) * 16384];
    bool pf = (tt + 1 < KSTEPS);
    ushort_t* dA = &lds[((tt + 1) & 1) * 16384];
    ushort_t* dB = &lds[32768 + ((tt + 1) & 1) * 16384];
    const ushort_t* sA = pa0 + (size_t)(tt + 1) * 65536;  // next K-step: 8 k-chunks * 1024 m * 8
    const ushort_t* sB = pb0 + (size_t)(tt + 1) * 64;
    s16x8 bf[4][2];

    // ---- phase 0: needs B0-3, A0, A2 of current tile ----
    asm volatile("s_waitcnt vmcnt(2)" ::: "memory");
    __builtin_amdgcn_s_barrier();
    __builtin_amdgcn_sched_barrier(0);
    if (pf) {
      gload_lds16(sB,              dB + l0);
      gload_lds16(sB + rowStrideB, dB + 4096 + l0);
    }
    #pragma unroll
    for (int nf = 0; nf < 4; ++nf)
      #pragma unroll
      for (int ks = 0; ks < 2; ++ks) {
        int row = wn + nf * 16 + llo;
        int ch = (ks * 4 + lhi) ^ (row & 7);
        bf[nf][ks] = *(const s16x8*)&Bb[row * 64 + ch * 8];
      }
    #pragma unroll
    for (int q = 0; q < 4; ++q) {
      if (q == 1 && pf) {
        gload_lds16(sB + 2 * rowStrideB, dB + 2 * 4096 + l0);
        gload_lds16(sB + 3 * rowStrideB, dB + 3 * 4096 + l0);
      }
      if (q == 2) {
        if (pf) asm volatile("s_waitcnt vmcnt(4)" ::: "memory");
        else    asm volatile("s_waitcnt vmcnt(0)" ::: "memory");
        __builtin_amdgcn_s_barrier();
        __builtin_amdgcn_sched_barrier(0);
        if (pf) {
          gload_lds16(sA,           dA + l0);
          gload_lds16(sA + 2 * 512, dA + 2 * 4096 + l0);
        }
      }
      if (q == 3 && pf) {
        gload_lds16(sA + 1 * 512, dA + 1 * 4096 + l0);
        gload_lds16(sA + 3 * 512, dA + 3 * 4096 + l0);
      }
      s16x8 af[2][2];
      #pragma unroll
      for (int j = 0; j < 2; ++j)
        #pragma unroll
        for (int ks = 0; ks < 2; ++ks) {
          int row = wm + (q * 2 + j) * 16 + llo;
          int ch = (ks * 4 + lhi) ^ (row & 7);
          af[j][ks] = *(const s16x8*)&Ab[row * 64 + ch * 8];
        }
      __builtin_amdgcn_s_setprio(1);
      #pragma unroll
      for (int j = 0; j < 2; ++j)
        #pragma unroll
        for (int nf = 0; nf < 4; ++nf)
          #pragma unroll
          for (int ks = 0; ks < 2; ++ks)
            acc[q * 2 + j][nf] = __builtin_amdgcn_mfma_f32_16x16x32_bf16(af[j][ks], bf[nf][ks], acc[q * 2 + j][nf], 0, 0, 0);
      __builtin_amdgcn_s_setprio(0);
    }
  }

  float* pbase = part + ((size_t)s << 20);
  #pragma unroll
  for (int mf = 0; mf < 8; ++mf)
    #pragma unroll
    for (int nf = 0; nf < 4; ++nf) {
      int n = n0 + wn + nf * 16 + llo;
      #pragma unroll
      for (int r = 0; r < 4; ++r) {
        int m = m0 + wm + mf * 16 + lhi * 4 + r;  // C layout: col=lane&15, row=(lane>>4)*4+reg
        pbase[(size_t)m * 1024 + n] = acc[mf][nf][r];
      }
    }
}

// ---------- reduce partials + bias + relu -> z1 ----------
__global__ __launch_bounds__(256) void k_red(const float* __restrict__ part,
                                             const float* __restrict__ bias,
                                             float* __restrict__ z1) {
  int idx = blockIdx.x * 256 + threadIdx.x;
  float a = bias[idx & 1023];
  #pragma unroll
  for (int s = 0; s < SPLITS; ++s) a += part[((size_t)s << 20) + idx];
  z1[idx] = fmaxf(a, 0.f);
}

// ---------- final layer: K=256 -> 1, wave reduction ----------
__global__ __launch_bounds__(256) void k_last(const float* __restrict__ z3,
                                              const float* __restrict__ w,
                                              const float* __restrict__ bias,
                                              float* __restrict__ out) {
  int t = threadIdx.x, l = t & 63, wv = t >> 6;
  int m = blockIdx.x * 4 + wv;
  float s = 0.f;
  #pragma unroll
  for (int c = 0; c < 4; ++c) s = fmaf(z3[(size_t)m * 256 + c * 64 + l], w[c * 64 + l], s);
  #pragma unroll
  for (int off = 32; off; off >>= 1) s += __shfl_down(s, off, 64);
  if (l == 0) out[m] = s + bias[0];
}

// ---------- fallback path (small workspace): fp32 fused-gen GEMM ----------
__global__ __launch_bounds__(256) void k_z1init(const float* __restrict__ bias, float* __restrict__ z1) {
  int idx = blockIdx.x * 256 + threadIdx.x;
  z1[idx] = bias[idx & 1023];
}
__global__ __launch_bounds__(256) void k_relu(float* __restrict__ z1) {
  int idx = blockIdx.x * 256 + threadIdx.x;
  z1[idx] = fmaxf(z1[idx], 0.f);
}
constexpr int FB_S = 8;
__global__ __launch_bounds__(256) void k_fbgemm(const float* __restrict__ xT,
                                                const int* __restrict__ iu,
                                                const float* __restrict__ tw0,
                                                float* __restrict__ z1) {
  __shared__ float zs[32 * 64];
  __shared__ float wsb[32 * 64];
  int t = threadIdx.x;
  int m0 = blockIdx.x * 64, n0 = blockIdx.y * 64, s = blockIdx.z;
  int kch = (K1 + FB_S - 1) / FB_S;
  int k0 = s * kch, kend = min(k0 + kch, K1);
  float acc[16];
  #pragma unroll
  for (int q = 0; q < 16; ++q) acc[q] = 0.f;
  int mm = t & 63, ng = t >> 6;
  for (int kk = k0; kk < kend; kk += 32) {
    __syncthreads();
    for (int sl = t; sl < 2048; sl += 256) {
      int kloc = sl >> 6, v6 = sl & 63;
      int k = kk + kloc;
      float zv = 0.f, wv = 0.f;
      if (k < kend) {
        int ij = iu[k];
        int i = ij & 0xFFFF, j = ij >> 16;
        zv = xT[(size_t)i * B_ + m0 + v6] * xT[(size_t)j * B_ + m0 + v6];
        wv = tw0[(size_t)k * 1024 + n0 + v6];
      }
      zs[kloc * 64 + v6] = zv;
      wsb[kloc * 64 + v6] = wv;
    }
    __syncthreads();
    #pragma unroll 4
    for (int kloc = 0; kloc < 32; ++kloc) {
      float zv = zs[kloc * 64 + mm];
      #pragma unroll
      for (int q = 0; q < 16; ++q)
        acc[q] = fmaf(zv, wsb[kloc * 64 + ng * 16 + q], acc[q]);
    }
  }
  #pragma unroll
  for (int q = 0; q < 16; ++q)
    atomicAdd(&z1[(size_t)(m0 + mm) * 1024 + n0 + ng * 16 + q], acc[q]);
}

extern "C" void kernel_launch(void* const* d_in, const int* in_sizes, int n_in,
                              void* d_out, int out_size, void* d_ws, size_t ws_size,
                              hipStream_t stream) {
  const float* dense  = (const float*)d_in[0];
  const int*   sparse = (const int*)  d_in[1];
  const float* emb    = (const float*)d_in[2];
  const float* bw0 = (const float*)d_in[3];  const float* bb0 = (const float*)d_in[4];
  const float* bw1 = (const float*)d_in[5];  const float* bb1 = (const float*)d_in[6];
  const float* bw2 = (const float*)d_in[7];  const float* bb2 = (const float*)d_in[8];
  const float* bw3 = (const float*)d_in[9];  const float* bb3 = (const float*)d_in[10];
  const float* tw0 = (const float*)d_in[11]; const float* tb0 = (const float*)d_in[12];
  const float* tw1 = (const float*)d_in[13]; const float* tb1 = (const float*)d_in[14];
  const float* tw2 = (const float*)d_in[15]; const float* tb2 = (const float*)d_in[16];
  const float* tw3 = (const float*)d_in[17]; const float* tb3 = (const float*)d_in[18];
  float* out = (float*)d_out;

  char* ws = (char*)d_ws;
  size_t off = 0;
  auto alloc = [&](size_t bytes) -> char* {
    char* p = ws + off;
    off = (off + bytes + 255) & ~(size_t)255;
    return p;
  };
  float* xT = (float*)alloc((size_t)434 * 1024 * 4);
  int*   iu = (int*)  alloc((size_t)Kp * 4);
  float* z1 = (float*)alloc((size_t)1024 * 1024 * 4);
  float* z2 = (float*)alloc((size_t)1024 * 512 * 4);
  float* z3 = (float*)alloc((size_t)1024 * 256 * 4);
  ushort_t* Z    = (ushort_t*)alloc((size_t)1024 * Kp * 2);
  ushort_t* WT   = (ushort_t*)alloc((size_t)1024 * Kp * 2);
  float*    part = (float*)   alloc((size_t)SPLITS * 1024 * 1024 * 4);
  bool big = (off <= ws_size);

  k_iu<<<368, 256, 0, stream>>>(iu, xT);
  k_bot<<<64, 256, 0, stream>>>(dense, bw0, bb0, bw1, bb1, bw2, bb2, bw3, bb3, xT);
  k_emb<<<dim3(26, 4), 256, 0, stream>>>(sparse, emb, xT);

  if (big) {
    k_genz<<<dim3(16, 184), 256, 0, stream>>>(xT, iu, Z);
    k_wt<<<dim3(368, 16), 256, 0, stream>>>(tw0, WT);
    k_gemm<<<256, 512, 0, stream>>>(Z, WT, part);
    k_red<<<4096, 256, 0, stream>>>(part, tb0, z1);
  } else {
    k_z1init<<<4096, 256, 0, stream>>>(tb0, z1);
    k_fbgemm<<<dim3(16, 16, FB_S), 256, 0, stream>>>(xT, iu, tw0, z1);
    k_relu<<<4096, 256, 0, stream>>>(z1);
  }

  k_sgemm<1024, 512><<<dim3(32, 8), 256, 0, stream>>>(z1, tw1, tb1, z2);
  k_sgemm<512, 256><<<dim3(32, 4), 256, 0, stream>>>(z2, tw2, tb2, z3);
  k_last<<<256, 256, 0, stream>>>(z3, tw3, tb3, out);
}

// Round 6
// 540.631 us; speedup vs baseline: 1.6793x; 1.0761x over previous
//
#include <hip/hip_runtime.h>
#include <stdint.h>

typedef unsigned short ushort_t;
typedef __attribute__((ext_vector_type(4))) float f32x4;
typedef __attribute__((ext_vector_type(8))) short s16x8;

#define DEVFN static __device__ __forceinline__

constexpr int B_   = 1024;
constexpr int P_   = 93528;   // upper-tri pairs of 432
constexpr int K1   = 93544;   // 16 + P_
constexpr int Kp   = 94208;   // padded K: 16 splits * 92 steps * 64
constexpr int SPLITS = 16;
constexpr int KCH  = Kp / SPLITS;  // 5888
constexpr int KSTEPS = KCH / 64;   // 92
// xT layout: [434][1024]; row 432 = ones, row 433 = zeros (branch-free products)

DEVFN ushort_t f2bf(float f) {
  union { float f; unsigned int u; } x; x.f = f;
  unsigned int r = x.u + 0x7FFFu + ((x.u >> 16) & 1u);
  return (ushort_t)(r >> 16);
}

DEVFN void gload_lds16(const void* g, void* l) {
  __builtin_amdgcn_global_load_lds((const __attribute__((address_space(1))) unsigned int*)g,
                                   (__attribute__((address_space(3))) unsigned int*)l, 16, 0, 0);
}

// ---------- fused pre-pass: iu table + xT pad rows | bottom MLP | embedding ----------
// grid: [0,368) iu, [368,432) bot, [432,536) emb
__global__ __launch_bounds__(256) void k_pre(const float* __restrict__ dense,
    const int* __restrict__ sparse, const float* __restrict__ tbl,
    const float* __restrict__ bw0, const float* __restrict__ bb0,
    const float* __restrict__ bw1, const float* __restrict__ bb1,
    const float* __restrict__ bw2, const float* __restrict__ bb2,
    const float* __restrict__ bw3, const float* __restrict__ bb3,
    int* __restrict__ iu, float* __restrict__ xT) {
  __shared__ float sm[13520];   // bot: xs 208 | h1 8192 | h2 4096 | h3 1024
  int bid = blockIdx.x, t = threadIdx.x;
  if (bid < 368) {
    // ---- iu + pad ----
    int k = bid * 256 + t;
    if (bid < 8) {
      int idx = bid * 256 + t;
      xT[432 * 1024 + idx] = (idx < 1024) ? 1.f : 0.f;
    }
    if (k >= Kp) return;
    int v;
    if (k < 16) v = k | (432 << 16);
    else if (k >= K1) v = 433 | (433 << 16);
    else {
      int p = k - 16;
      float s = sqrtf((float)(748225 - 8 * p));      // 865^2
      int i = (int)((865.0f - s) * 0.5f);
      if (i < 0) i = 0; if (i > 431) i = 431;
      while (i < 431 && (i + 1) * (865 - (i + 1)) / 2 <= p) ++i;
      while (i > 0 && i * (865 - i) / 2 > p) --i;
      int j = i + (p - i * (865 - i) / 2);
      v = i | (j << 16);
    }
    iu[k] = v;
  } else if (bid < 432) {
    // ---- bottom MLP: 13->512->256->64->16, 16 rows/block ----
    float* xs = sm;
    float* h1 = sm + 208;
    float* h2 = h1 + 8192;
    float* h3 = h2 + 4096;
    int m0 = (bid - 368) * 16;
    if (t < 208) xs[t] = dense[m0 * 13 + t];
    __syncthreads();
    #pragma unroll
    for (int h = 0; h < 2; ++h) {
      int n = h * 256 + t;
      float a[16];
      float bv = bb0[n];
      #pragma unroll
      for (int r = 0; r < 16; ++r) a[r] = bv;
      for (int k = 0; k < 13; ++k) {
        float w = bw0[k * 512 + n];
        #pragma unroll
        for (int r = 0; r < 16; ++r) a[r] = fmaf(xs[r * 13 + k], w, a[r]);
      }
      #pragma unroll
      for (int r = 0; r < 16; ++r) h1[r * 512 + n] = fmaxf(a[r], 0.f);
    }
    __syncthreads();
    {
      int n = t;
      float a[16];
      float bv = bb1[n];
      #pragma unroll
      for (int r = 0; r < 16; ++r) a[r] = bv;
      for (int k = 0; k < 512; ++k) {
        float w = bw1[k * 256 + n];
        #pragma unroll
        for (int r = 0; r < 16; ++r) a[r] = fmaf(h1[r * 512 + k], w, a[r]);
      }
      #pragma unroll
      for (int r = 0; r < 16; ++r) h2[r * 256 + n] = fmaxf(a[r], 0.f);
    }
    __syncthreads();
    {
      int n = t & 63, r0 = t >> 6;
      float a[4];
      float bv = bb2[n];
      #pragma unroll
      for (int i = 0; i < 4; ++i) a[i] = bv;
      for (int k = 0; k < 256; ++k) {
        float w = bw2[k * 64 + n];
        #pragma unroll
        for (int i = 0; i < 4; ++i) a[i] = fmaf(h2[(r0 + 4 * i) * 256 + k], w, a[i]);
      }
      #pragma unroll
      for (int i = 0; i < 4; ++i) h3[(r0 + 4 * i) * 64 + n] = fmaxf(a[i], 0.f);
    }
    __syncthreads();
    {
      int n = t & 15, r = t >> 4;
      float a = bb3[n];
      for (int k = 0; k < 64; ++k) a = fmaf(h3[r * 64 + k], bw3[k * 16 + n], a);
      xT[(size_t)n * B_ + m0 + r] = fmaxf(a, 0.f);
    }
  } else {
    // ---- embedding gather into xT rows 16..431 ----
    int e = bid - 432;
    int f = e >> 2;
    int b = (e & 3) * 256 + t;
    int idx = sparse[(size_t)b * 26 + f];
    const float4* src = (const float4*)(tbl + ((size_t)f * 100000 + idx) * 16);
    #pragma unroll
    for (int q = 0; q < 4; ++q) {
      float4 v = src[q];
      int r = 16 + f * 16 + q * 4;
      xT[(size_t)(r + 0) * B_ + b] = v.x;
      xT[(size_t)(r + 1) * B_ + b] = v.y;
      xT[(size_t)(r + 2) * B_ + b] = v.z;
      xT[(size_t)(r + 3) * B_ + b] = v.w;
    }
  }
}

// ---------- fused Z-gen + W-transpose ----------
// grid 8832; bid%3==0 -> genz (2944 blocks), else -> wt (5888 blocks)
__global__ __launch_bounds__(256, 4) void k_gz(const float* __restrict__ xT,
                                               const int* __restrict__ iu,
                                               const float* __restrict__ tw0,
                                               ushort_t* __restrict__ Z,
                                               ushort_t* __restrict__ WT) {
  __shared__ char smem[256 * 68 * 2];   // wt: 34816 B; genz reuses first 2 KB
  int bid = blockIdx.x, t = threadIdx.x;
  int r3 = bid % 3;
  if (r3 == 0) {
    // ---- Z generation: blocked layout Z[(k/8)][m][8] ----
    int idx = bid / 3;
    int* ls_iu = (int*)smem;
    int l = t & 63, w = t >> 6;
    int mb = (idx & 15) * 64;
    int kt = (idx >> 4) * 512;
    ls_iu[t] = iu[kt + t];
    ls_iu[256 + t] = iu[kt + 256 + t];
    __syncthreads();
    uint32_t moff = mb + l;
    int kw = w * 128;
    #pragma unroll 2
    for (int g = 0; g < 16; ++g) {
      int kloc = kw + g * 8;
      int4 ij0 = *(const int4*)&ls_iu[kloc];
      int4 ij1 = *(const int4*)&ls_iu[kloc + 4];
      float p[8];
      {
        int v0 = ij0.x, v1 = ij0.y, v2 = ij0.z, v3 = ij0.w;
        p[0] = xT[(uint32_t)((v0 & 0xFFFF) << 10) + moff] * xT[(uint32_t)((v0 >> 16) << 10) + moff];
        p[1] = xT[(uint32_t)((v1 & 0xFFFF) << 10) + moff] * xT[(uint32_t)((v1 >> 16) << 10) + moff];
        p[2] = xT[(uint32_t)((v2 & 0xFFFF) << 10) + moff] * xT[(uint32_t)((v2 >> 16) << 10) + moff];
        p[3] = xT[(uint32_t)((v3 & 0xFFFF) << 10) + moff] * xT[(uint32_t)((v3 >> 16) << 10) + moff];
        v0 = ij1.x; v1 = ij1.y; v2 = ij1.z; v3 = ij1.w;
        p[4] = xT[(uint32_t)((v0 & 0xFFFF) << 10) + moff] * xT[(uint32_t)((v0 >> 16) << 10) + moff];
        p[5] = xT[(uint32_t)((v1 & 0xFFFF) << 10) + moff] * xT[(uint32_t)((v1 >> 16) << 10) + moff];
        p[6] = xT[(uint32_t)((v2 & 0xFFFF) << 10) + moff] * xT[(uint32_t)((v2 >> 16) << 10) + moff];
        p[7] = xT[(uint32_t)((v3 & 0xFFFF) << 10) + moff] * xT[(uint32_t)((v3 >> 16) << 10) + moff];
      }
      union { uint32_t w4[4]; int4 v4; } o;
      asm("v_cvt_pk_bf16_f32 %0, %1, %2" : "=v"(o.w4[0]) : "v"(p[0]), "v"(p[1]));
      asm("v_cvt_pk_bf16_f32 %0, %1, %2" : "=v"(o.w4[1]) : "v"(p[2]), "v"(p[3]));
      asm("v_cvt_pk_bf16_f32 %0, %1, %2" : "=v"(o.w4[2]) : "v"(p[4]), "v"(p[5]));
      asm("v_cvt_pk_bf16_f32 %0, %1, %2" : "=v"(o.w4[3]) : "v"(p[6]), "v"(p[7]));
      int kglob = kt + kloc;
      *(int4*)&Z[((size_t)(kglob >> 3) * 1024 + moff) * 8] = o.v4;
    }
  } else {
    // ---- WT: transpose tw0 (K1 x 1024 f32) -> WT (1024 x Kp bf16), 256k x 64n tile ----
    int idx = (bid / 3) * 2 + r3 - 1;
    ushort_t* ls = (ushort_t*)smem;
    int k0 = (idx % 368) * 256, n0 = (idx / 368) * 64;
    int kr = t >> 2, c4 = t & 3;
    #pragma unroll
    for (int pass = 0; pass < 4; ++pass) {
      int kl = pass * 64 + kr;
      int k = k0 + kl;
      #pragma unroll
      for (int q = 0; q < 4; ++q) {
        float4 v = make_float4(0.f, 0.f, 0.f, 0.f);
        if (k < K1) v = *(const float4*)&tw0[(size_t)k * 1024 + n0 + q * 16 + c4 * 4];
        ushort_t* d = &ls[kl * 68 + q * 16 + c4 * 4];
        d[0] = f2bf(v.x); d[1] = f2bf(v.y); d[2] = f2bf(v.z); d[3] = f2bf(v.w);
      }
    }
    __syncthreads();
    int nl = t >> 2, kq = t & 3;
    ushort_t* dst = WT + (size_t)(n0 + nl) * Kp + k0 + kq * 64;
    #pragma unroll
    for (int j = 0; j < 8; ++j) {
      union { ushort_t u[8]; int4 v; } o;
      #pragma unroll
      for (int e = 0; e < 8; ++e) o.u[e] = ls[(kq * 64 + j * 8 + e) * 68 + nl];
      *(int4*)(dst + j * 8) = o.v;
    }
  }
}

// ---------- main bf16 GEMM: deep counted-vmcnt pipeline, PINNED phases ----------
// A (blocked Z) dbuf; B dbuf issued 2 K-steps ahead (B[tt] LDS dead after q0 reads,
// which are pinned complete by lgkmcnt(0)+sched_barrier BEFORE the q0 MFMA cluster,
// which precedes the q2 barrier after which B[tt+2] issues).
// Issue: A[tt+1]{0,2}@q0, A[tt+1]{1,3}@q1, B[tt+2]{0-3}@q2.
// Waits: vmcnt(6)@q0, vmcnt(8)@q2 (steady); drains on last step.
__global__ __launch_bounds__(512, 2) void k_gemm(const ushort_t* __restrict__ Z,
                                                 const ushort_t* __restrict__ WT,
                                                 float* __restrict__ part) {
  __shared__ ushort_t lds[65536];   // A: [2][16384] at 0; B: [2][16384] at 32768 (128 KB)
  int t = threadIdx.x;
  int bid = blockIdx.x;
  int s = bid >> 4, tile = bid & 15;
  int m0 = (tile >> 2) * 256, n0 = (tile & 3) * 256;
  int kb = s * KCH;

  int rr = t >> 3, cc = t & 7;
  int cs = cc ^ (rr & 7);                          // inverse swizzle on global source
  const ushort_t* pa0 = Z + (((size_t)(kb >> 3) + cs) * 1024 + m0 + rr) * 8;
  const ushort_t* pb0 = WT + (size_t)(n0 + rr) * Kp + kb + cs * 8;
  const size_t rowStrideB = (size_t)64 * Kp;
  int l0 = t * 8;

  int w = t >> 6, l = t & 63;
  int wm = (w >> 2) * 128, wn = (w & 3) * 64;
  int lhi = l >> 4, llo = l & 15;

  f32x4 acc[8][4];
  #pragma unroll
  for (int a = 0; a < 8; ++a)
    #pragma unroll
    for (int b = 0; b < 4; ++b) acc[a][b] = f32x4{0.f, 0.f, 0.f, 0.f};

  // prologue (canonical order, no drain): B[0]x4, A[0]{0,2}, A[0]{1,3}, B[1]x4
  #pragma unroll
  for (int i = 0; i < 4; ++i)
    gload_lds16(pb0 + i * rowStrideB, &lds[32768 + i * 4096 + l0]);
  gload_lds16(pa0,           &lds[0 * 4096 + l0]);
  gload_lds16(pa0 + 2 * 512, &lds[2 * 4096 + l0]);
  gload_lds16(pa0 + 1 * 512, &lds[1 * 4096 + l0]);
  gload_lds16(pa0 + 3 * 512, &lds[3 * 4096 + l0]);
  #pragma unroll
  for (int i = 0; i < 4; ++i)
    gload_lds16(pb0 + 64 + i * rowStrideB, &lds[32768 + 16384 + i * 4096 + l0]);

  for (int tt = 0; tt < KSTEPS; ++tt) {
    const ushort_t* Ab = &lds[(tt & 1) * 16384];
    const ushort_t* Bb = &lds[32768 + (tt & 1) * 16384];
    bool pf  = (tt + 1 < KSTEPS);
    bool pf2 = (tt + 2 < KSTEPS);
    ushort_t* dA  = &lds[((tt + 1) & 1) * 16384];
    ushort_t* dB2 = &lds[32768 + (tt & 1) * 16384];       // B[tt+2] parity == tt
    const ushort_t* sA  = pa0 + (size_t)(tt + 1) * 65536; // next K-step: 8 k-chunks * 1024 m * 8
    const ushort_t* sB2 = pb0 + (size_t)(tt + 2) * 64;
    s16x8 bf[4][2];

    // ---- q0 boundary: needs B[tt] (all) + A[tt]{0,2} ----
    if (pf) asm volatile("s_waitcnt vmcnt(6)" ::: "memory");
    else    asm volatile("s_waitcnt vmcnt(2)" ::: "memory");
    __builtin_amdgcn_s_barrier();
    __builtin_amdgcn_sched_barrier(0);
    if (pf) {
      gload_lds16(sA,           dA + l0);
      gload_lds16(sA + 2 * 512, dA + 2 * 4096 + l0);
    }
    #pragma unroll
    for (int nf = 0; nf < 4; ++nf)
      #pragma unroll
      for (int ks = 0; ks < 2; ++ks) {
        int row = wn + nf * 16 + llo;
        int ch = (ks * 4 + lhi) ^ (row & 7);
        bf[nf][ks] = *(const s16x8*)&Bb[row * 64 + ch * 8];
      }
    #pragma unroll
    for (int q = 0; q < 4; ++q) {
      if (q == 1 && pf) {
        gload_lds16(sA + 1 * 512, dA + 1 * 4096 + l0);
        gload_lds16(sA + 3 * 512, dA + 3 * 4096 + l0);
      }
      if (q == 2) {
        if (pf) asm volatile("s_waitcnt vmcnt(8)" ::: "memory");
        else    asm volatile("s_waitcnt vmcnt(0)" ::: "memory");
        __builtin_amdgcn_s_barrier();
        __builtin_amdgcn_sched_barrier(0);
        if (pf2) {
          #pragma unroll
          for (int i = 0; i < 4; ++i)
            gload_lds16(sB2 + i * rowStrideB, dB2 + i * 4096 + l0);
        }
      }
      s16x8 af[2][2];
      #pragma unroll
      for (int j = 0; j < 2; ++j)
        #pragma unroll
        for (int ks = 0; ks < 2; ++ks) {
          int row = wm + (q * 2 + j) * 16 + llo;
          int ch = (ks * 4 + lhi) ^ (row & 7);
          af[j][ks] = *(const s16x8*)&Ab[row * 64 + ch * 8];
        }
      // PIN: ds_reads complete here, before this phase's MFMA cluster; nothing
      // crosses this point in either direction (rule #18 discipline).
      asm volatile("s_waitcnt lgkmcnt(0)" ::: "memory");
      __builtin_amdgcn_sched_barrier(0);
      __builtin_amdgcn_s_setprio(1);
      #pragma unroll
      for (int j = 0; j < 2; ++j)
        #pragma unroll
        for (int nf = 0; nf < 4; ++nf)
          #pragma unroll
          for (int ks = 0; ks < 2; ++ks)
            acc[q * 2 + j][nf] = __builtin_amdgcn_mfma_f32_16x16x32_bf16(af[j][ks], bf[nf][ks], acc[q * 2 + j][nf], 0, 0, 0);
      __builtin_amdgcn_s_setprio(0);
      __builtin_amdgcn_sched_barrier(0);
    }
  }

  float* pbase = part + ((size_t)s << 20);
  #pragma unroll
  for (int mf = 0; mf < 8; ++mf)
    #pragma unroll
    for (int nf = 0; nf < 4; ++nf) {
      int n = n0 + wn + nf * 16 + llo;
      #pragma unroll
      for (int r = 0; r < 4; ++r) {
        int m = m0 + wm + mf * 16 + lhi * 4 + r;  // C layout: col=lane&15, row=(lane>>4)*4+reg
        pbase[(size_t)m * 1024 + n] = acc[mf][nf][r];
      }
    }
}

// ---------- reduce partials + bias + relu -> z1 ----------
__global__ __launch_bounds__(256) void k_red(const float* __restrict__ part,
                                             const float* __restrict__ bias,
                                             float* __restrict__ z1) {
  int idx = blockIdx.x * 256 + threadIdx.x;
  float a = bias[idx & 1023];
  #pragma unroll
  for (int s = 0; s < SPLITS; ++s) a += part[((size_t)s << 20) + idx];
  z1[idx] = fmaxf(a, 0.f);
}

// ---------- tiled fp32 SGEMM for top MLP: C=relu(A@W+b), 32x64 tile ----------
template<int K, int N>
__global__ __launch_bounds__(256) void k_sgemm(const float* __restrict__ A,
                                               const float* __restrict__ W,
                                               const float* __restrict__ bias,
                                               float* __restrict__ C) {
  __shared__ float As[16][34];
  __shared__ float Bs[16][68];
  int t = threadIdx.x;
  int m0 = blockIdx.x * 32, n0 = blockIdx.y * 64;
  int tx = t & 15, ty = t >> 4;
  float acc[2][4];
  #pragma unroll
  for (int j = 0; j < 2; ++j)
    #pragma unroll
    for (int q = 0; q < 4; ++q) acc[j][q] = 0.f;
  int ar = t >> 3, ak = (t & 7) * 2;
  int bk = t >> 4, bn = (t & 15) * 4;
  for (int k0 = 0; k0 < K; k0 += 16) {
    float2 av = *(const float2*)&A[(size_t)(m0 + ar) * K + k0 + ak];
    float4 bv = *(const float4*)&W[(size_t)(k0 + bk) * N + n0 + bn];
    __syncthreads();
    As[ak][ar] = av.x; As[ak + 1][ar] = av.y;
    *(float4*)&Bs[bk][bn] = bv;
    __syncthreads();
    #pragma unroll
    for (int k = 0; k < 16; ++k) {
      float2 a = *(const float2*)&As[k][ty * 2];
      float4 b = *(const float4*)&Bs[k][tx * 4];
      acc[0][0] = fmaf(a.x, b.x, acc[0][0]); acc[0][1] = fmaf(a.x, b.y, acc[0][1]);
      acc[0][2] = fmaf(a.x, b.z, acc[0][2]); acc[0][3] = fmaf(a.x, b.w, acc[0][3]);
      acc[1][0] = fmaf(a.y, b.x, acc[1][0]); acc[1][1] = fmaf(a.y, b.y, acc[1][1]);
      acc[1][2] = fmaf(a.y, b.z, acc[1][2]); acc[1][3] = fmaf(a.y, b.w, acc[1][3]);
    }
  }
  #pragma unroll
  for (int j = 0; j < 2; ++j) {
    int m = m0 + ty * 2 + j;
    float4 o;
    o.x = fmaxf(acc[j][0] + bias[n0 + tx * 4 + 0], 0.f);
    o.y = fmaxf(acc[j][1] + bias[n0 + tx * 4 + 1], 0.f);
    o.z = fmaxf(acc[j][2] + bias[n0 + tx * 4 + 2], 0.f);
    o.w = fmaxf(acc[j][3] + bias[n0 + tx * 4 + 3], 0.f);
    *(float4*)&C[(size_t)m * N + n0 + tx * 4] = o;
  }
}

// ---------- final layer: K=256 -> 1, wave reduction ----------
__global__ __launch_bounds__(256) void k_last(const float* __restrict__ z3,
                                              const float* __restrict__ w,
                                              const float* __restrict__ bias,
                                              float* __restrict__ out) {
  int t = threadIdx.x, l = t & 63, wv = t >> 6;
  int m = blockIdx.x * 4 + wv;
  float s = 0.f;
  #pragma unroll
  for (int c = 0; c < 4; ++c) s = fmaf(z3[(size_t)m * 256 + c * 64 + l], w[c * 64 + l], s);
  #pragma unroll
  for (int off = 32; off; off >>= 1) s += __shfl_down(s, off, 64);
  if (l == 0) out[m] = s + bias[0];
}

// ---------- fallback path (small workspace): fp32 fused-gen GEMM ----------
__global__ __launch_bounds__(256) void k_z1init(const float* __restrict__ bias, float* __restrict__ z1) {
  int idx = blockIdx.x * 256 + threadIdx.x;
  z1[idx] = bias[idx & 1023];
}
__global__ __launch_bounds__(256) void k_relu(float* __restrict__ z1) {
  int idx = blockIdx.x * 256 + threadIdx.x;
  z1[idx] = fmaxf(z1[idx], 0.f);
}
constexpr int FB_S = 8;
__global__ __launch_bounds__(256) void k_fbgemm(const float* __restrict__ xT,
                                                const int* __restrict__ iu,
                                                const float* __restrict__ tw0,
                                                float* __restrict__ z1) {
  __shared__ float zs[32 * 64];
  __shared__ float wsb[32 * 64];
  int t = threadIdx.x;
  int m0 = blockIdx.x * 64, n0 = blockIdx.y * 64, s = blockIdx.z;
  int kch = (K1 + FB_S - 1) / FB_S;
  int k0 = s * kch, kend = min(k0 + kch, K1);
  float acc[16];
  #pragma unroll
  for (int q = 0; q < 16; ++q) acc[q] = 0.f;
  int mm = t & 63, ng = t >> 6;
  for (int kk = k0; kk < kend; kk += 32) {
    __syncthreads();
    for (int sl = t; sl < 2048; sl += 256) {
      int kloc = sl >> 6, v6 = sl & 63;
      int k = kk + kloc;
      float zv = 0.f, wv = 0.f;
      if (k < kend) {
        int ij = iu[k];
        int i = ij & 0xFFFF, j = ij >> 16;
        zv = xT[(size_t)i * B_ + m0 + v6] * xT[(size_t)j * B_ + m0 + v6];
        wv = tw0[(size_t)k * 1024 + n0 + v6];
      }
      zs[kloc * 64 + v6] = zv;
      wsb[kloc * 64 + v6] = wv;
    }
    __syncthreads();
    #pragma unroll 4
    for (int kloc = 0; kloc < 32; ++kloc) {
      float zv = zs[kloc * 64 + mm];
      #pragma unroll
      for (int q = 0; q < 16; ++q)
        acc[q] = fmaf(zv, wsb[kloc * 64 + ng * 16 + q], acc[q]);
    }
  }
  #pragma unroll
  for (int q = 0; q < 16; ++q)
    atomicAdd(&z1[(size_t)(m0 + mm) * 1024 + n0 + ng * 16 + q], acc[q]);
}

extern "C" void kernel_launch(void* const* d_in, const int* in_sizes, int n_in,
                              void* d_out, int out_size, void* d_ws, size_t ws_size,
                              hipStream_t stream) {
  const float* dense  = (const float*)d_in[0];
  const int*   sparse = (const int*)  d_in[1];
  const float* emb    = (const float*)d_in[2];
  const float* bw0 = (const float*)d_in[3];  const float* bb0 = (const float*)d_in[4];
  const float* bw1 = (const float*)d_in[5];  const float* bb1 = (const float*)d_in[6];
  const float* bw2 = (const float*)d_in[7];  const float* bb2 = (const float*)d_in[8];
  const float* bw3 = (const float*)d_in[9];  const float* bb3 = (const float*)d_in[10];
  const float* tw0 = (const float*)d_in[11]; const float* tb0 = (const float*)d_in[12];
  const float* tw1 = (const float*)d_in[13]; const float* tb1 = (const float*)d_in[14];
  const float* tw2 = (const float*)d_in[15]; const float* tb2 = (const float*)d_in[16];
  const float* tw3 = (const float*)d_in[17]; const float* tb3 = (const float*)d_in[18];
  float* out = (float*)d_out;

  char* ws = (char*)d_ws;
  size_t off = 0;
  auto alloc = [&](size_t bytes) -> char* {
    char* p = ws + off;
    off = (off + bytes + 255) & ~(size_t)255;
    return p;
  };
  float* xT = (float*)alloc((size_t)434 * 1024 * 4);
  int*   iu = (int*)  alloc((size_t)Kp * 4);
  float* z1 = (float*)alloc((size_t)1024 * 1024 * 4);
  float* z2 = (float*)alloc((size_t)1024 * 512 * 4);
  float* z3 = (float*)alloc((size_t)1024 * 256 * 4);
  ushort_t* Z    = (ushort_t*)alloc((size_t)1024 * Kp * 2);
  ushort_t* WT   = (ushort_t*)alloc((size_t)1024 * Kp * 2);
  float*    part = (float*)   alloc((size_t)SPLITS * 1024 * 1024 * 4);
  bool big = (off <= ws_size);

  k_pre<<<536, 256, 0, stream>>>(dense, sparse, emb, bw0, bb0, bw1, bb1, bw2, bb2, bw3, bb3, iu, xT);

  if (big) {
    k_gz<<<8832, 256, 0, stream>>>(xT, iu, tw0, Z, WT);
    k_gemm<<<256, 512, 0, stream>>>(Z, WT, part);
    k_red<<<4096, 256, 0, stream>>>(part, tb0, z1);
  } else {
    k_z1init<<<4096, 256, 0, stream>>>(tb0, z1);
    k_fbgemm<<<dim3(16, 16, FB_S), 256, 0, stream>>>(xT, iu, tw0, z1);
    k_relu<<<4096, 256, 0, stream>>>(z1);
  }

  k_sgemm<1024, 512><<<dim3(32, 8), 256, 0, stream>>>(z1, tw1, tb1, z2);
  k_sgemm<512, 256><<<dim3(32, 4), 256, 0, stream>>>(z2, tw2, tb2, z3);
  k_last<<<256, 256, 0, stream>>>(z3, tw3, tb3, out);
}